// Round 11
// baseline (31718.292 us; speedup 1.0000x reference)
//
#include <hip/hip_runtime.h>
#include <math.h>
#include <stdint.h>

typedef unsigned long long u64;
typedef unsigned int u32;

// ============ L1: conv3x3(256->256,f64 acc)+bias+relu + heads; f32 outputs ==
__global__ __launch_bounds__(256) void k_conv_lit(
    const float* __restrict__ x, const float* __restrict__ cw,
    const float* __restrict__ cb, const float* __restrict__ clsw,
    const float* __restrict__ clsb, const float* __restrict__ bbw,
    const float* __restrict__ bbb, float* __restrict__ scores,
    float* __restrict__ deltas, int H, int W) {
    __shared__ __align__(16) float patch[2304];
    __shared__ double hs[256];
    __shared__ double hout[18];
    int pos = blockIdx.x;
    int row = pos / W, col = pos % W;
    int tid = threadIdx.x;
    for (int t = tid; t < 2304; t += 256) {
        int ci = t / 9, k = t % 9;
        int ky = k / 3, kx = k % 3;
        int gy = row - 1 + ky, gx = col - 1 + kx;
        float v = 0.f;
        if (gy >= 0 && gy < H && gx >= 0 && gx < W)
            v = x[((size_t)ci * H + gy) * W + gx];
        patch[t] = v;
    }
    __syncthreads();
    double acc = 0.0;
    const float4* w4 = (const float4*)(cw + (size_t)tid * 2304);
    const float4* p4 = (const float4*)patch;
    for (int t = 0; t < 576; ++t) {
        float4 wv = w4[t], pv = p4[t];
        acc = fma((double)wv.x, (double)pv.x, acc);
        acc = fma((double)wv.y, (double)pv.y, acc);
        acc = fma((double)wv.z, (double)pv.z, acc);
        acc = fma((double)wv.w, (double)pv.w, acc);
    }
    hs[tid] = fmax(acc + (double)cb[tid], 0.0);
    __syncthreads();
    if (tid < 18) {
        double s = (tid < 6) ? (double)clsb[tid] : (double)bbb[tid - 6];
        const float* hv = (tid < 6) ? (clsw + tid * 256) : (bbw + (tid - 6) * 256);
        for (int ci = 0; ci < 256; ++ci) s += (double)hv[ci] * hs[ci];
        hout[tid] = s;
    }
    __syncthreads();
    // f32 softmax with max-subtraction (mirror jax.nn.softmax / np)
    if (tid < 3) {
        float c0 = (float)hout[tid], c1 = (float)hout[3 + tid];
        float m = fmaxf(c0, c1);
        float e0 = expf(__fsub_rn(c0, m));
        float e1 = expf(__fsub_rn(c1, m));
        scores[(size_t)pos * 3 + tid] = __fdiv_rn(e1, __fadd_rn(e0, e1));
    }
    if (tid < 12) {
        int a = tid >> 2, c = tid & 3;
        deltas[((size_t)pos * 3 + a) * 4 + c] = (float)hout[6 + tid];
    }
}

// ============ L2: per-level top-k (argmax removal, f32 keys) + f32 decode ===
struct TArgs {
    const float* sc[5];
    const float* dl[5];
    float* ts[5];
    int* ti[5];
    float* boxes[5];
    float* areas[5];
    int N[5], K[5], W[5];
    float stride[5];
    float anc[5][12];
    const float* im_info;
};

__global__ __launch_bounds__(1024) void k_topk_lit(TArgs a) {
    __shared__ u64 taken[3072];
    __shared__ float cbv[1024];
    __shared__ u32 cbi[1024];
    __shared__ float bv[1024];
    __shared__ u32 bi[1024];
    int l = blockIdx.x;
    const float* sc = a.sc[l];
    int N = a.N[l], K = a.K[l];
    int tid = threadIdx.x;
    int nw = (N + 63) >> 6;
    for (int i = tid; i < nw; i += 1024) taken[i] = 0ull;
    {
        float best = -1.0f;
        u32 bidx = 0xFFFFFFFFu;
        for (int i = tid; i < N; i += 1024) {
            float v = sc[i];
            if (v > best) { best = v; bidx = (u32)i; }  // strict: lowest idx kept
        }
        cbv[tid] = best;
        cbi[tid] = bidx;
    }
    __syncthreads();
    for (int r = 0; r < K; ++r) {
        bv[tid] = cbv[tid];
        bi[tid] = cbi[tid];
        __syncthreads();
        for (int ofs = 512; ofs > 0; ofs >>= 1) {
            if (tid < ofs) {
                float vo = bv[tid + ofs];
                u32 io = bi[tid + ofs];
                if (vo > bv[tid] || (vo == bv[tid] && io < bi[tid])) {
                    bv[tid] = vo;
                    bi[tid] = io;
                }
            }
            __syncthreads();
        }
        u32 j = bi[0];
        if (tid == 0) {
            a.ts[l][r] = bv[0];
            a.ti[l][r] = (int)j;
            taken[j >> 6] |= (1ull << (j & 63));
        }
        __syncthreads();
        u32 o = j & 1023u;
        {
            u32 i = o + ((u32)tid << 10);
            float v2 = -1.0f;
            u32 i2 = 0xFFFFFFFFu;
            if (i < (u32)N && !((taken[i >> 6] >> (i & 63)) & 1ull)) {
                v2 = sc[i];
                i2 = i;
            }
            bv[tid] = v2;
            bi[tid] = i2;
        }
        __syncthreads();
        for (int ofs = 512; ofs > 0; ofs >>= 1) {
            if (tid < ofs) {
                float vo = bv[tid + ofs];
                u32 io = bi[tid + ofs];
                if (vo > bv[tid] || (vo == bv[tid] && io < bi[tid])) {
                    bv[tid] = vo;
                    bi[tid] = io;
                }
            }
            __syncthreads();
        }
        if (tid == 0) {
            cbv[o] = bv[0];
            cbi[o] = bi[0];
        }
        __syncthreads();
    }
    // f32 step-wise decode + clip (mirror np elementwise rounding; no fma)
    float imh = a.im_info[0], imw = a.im_info[1];
    float hi_x = __fsub_rn(imw, 1.0f), hi_y = __fsub_rn(imh, 1.0f);
    if (tid < K) {
        int idx = a.ti[l][tid];
        int aidx = idx % 3;
        int posi = idx / 3;
        int W = a.W[l];
        int rr = posi / W, cc = posi % W;
        float sx = __fmul_rn((float)cc, a.stride[l]);
        float sy = __fmul_rn((float)rr, a.stride[l]);
        const float* an = &a.anc[l][aidx * 4];
        float ax1 = __fadd_rn(an[0], sx), ay1 = __fadd_rn(an[1], sy);
        float ax2 = __fadd_rn(an[2], sx), ay2 = __fadd_rn(an[3], sy);
        float w = __fadd_rn(__fsub_rn(ax2, ax1), 1.0f);
        float h = __fadd_rn(__fsub_rn(ay2, ay1), 1.0f);
        float cx = __fadd_rn(ax1, __fmul_rn(0.5f, w));
        float cy = __fadd_rn(ay1, __fmul_rn(0.5f, h));
        const float* d = &a.dl[l][(size_t)idx * 4];
        float dx = d[0], dy = d[1];
        float dw = fminf(d[2], 4.135166556742356f);
        float dh = fminf(d[3], 4.135166556742356f);
        float pcx = __fadd_rn(__fmul_rn(dx, w), cx);
        float pcy = __fadd_rn(__fmul_rn(dy, h), cy);
        float pw = __fmul_rn(expf(dw), w);
        float ph = __fmul_rn(expf(dh), h);
        float hw2 = __fmul_rn(0.5f, pw), hh2 = __fmul_rn(0.5f, ph);
        float x1 = __fsub_rn(pcx, hw2);
        float y1 = __fsub_rn(pcy, hh2);
        float x2 = __fsub_rn(__fadd_rn(pcx, hw2), 1.0f);
        float y2 = __fsub_rn(__fadd_rn(pcy, hh2), 1.0f);
        x1 = fminf(fmaxf(x1, 0.0f), hi_x);
        y1 = fminf(fmaxf(y1, 0.0f), hi_y);
        x2 = fminf(fmaxf(x2, 0.0f), hi_x);
        y2 = fminf(fmaxf(y2, 0.0f), hi_y);
        float* obx = &a.boxes[l][(size_t)tid * 4];
        obx[0] = x1;
        obx[1] = y1;
        obx[2] = x2;
        obx[3] = y2;
        a.areas[l][tid] = __fmul_rn(__fadd_rn(__fsub_rn(x2, x1), 1.0f),
                                    __fadd_rn(__fsub_rn(y2, y1), 1.0f));
    }
}

// ============ L3: literal NMS (f32 IoU, mirror np ops) ======================
struct NArgs {
    const float* ts[5];
    const float* boxes[5];
    const float* areas[5];
    int K[5];
    int* keep[5];
    int* nkeep[5];
};

__global__ __launch_bounds__(1024) void k_nms_lit(NArgs a) {
    __shared__ float bv[1024];
    __shared__ u32 bi[1024];
    __shared__ unsigned char act[1024];
    __shared__ float jb[5];
    int l = blockIdx.x;
    int K = a.K[l];
    const float* ts = a.ts[l];
    const float* bx = a.boxes[l];
    const float* ar = a.areas[l];
    int tid = threadIdx.x;
    act[tid] = (tid < K) ? 1 : 0;
    float myx1 = 0, myy1 = 0, myx2 = 0, myy2 = 0, mya = 0, mys = 0;
    if (tid < K) {
        myx1 = bx[tid * 4];
        myy1 = bx[tid * 4 + 1];
        myx2 = bx[tid * 4 + 2];
        myy2 = bx[tid * 4 + 3];
        mya = ar[tid];
        mys = ts[tid];
    }
    __syncthreads();
    int nk = 0;
    for (int it = 0; it < K; ++it) {
        bv[tid] = (tid < K && act[tid]) ? mys : -1.0f;
        bi[tid] = (tid < K && act[tid]) ? (u32)tid : 0xFFFFFFFFu;
        __syncthreads();
        for (int ofs = 512; ofs > 0; ofs >>= 1) {
            if (tid < ofs) {
                float vo = bv[tid + ofs];
                u32 io = bi[tid + ofs];
                if (vo > bv[tid] || (vo == bv[tid] && io < bi[tid])) {
                    bv[tid] = vo;
                    bi[tid] = io;
                }
            }
            __syncthreads();
        }
        u32 j = bi[0];
        bool valid = (j != 0xFFFFFFFFu);
        if (tid == 0) a.keep[l][it] = valid ? (int)j : -1;
        if (valid) {
            if (tid == 0) {
                jb[0] = bx[j * 4];
                jb[1] = bx[j * 4 + 1];
                jb[2] = bx[j * 4 + 2];
                jb[3] = bx[j * 4 + 3];
                jb[4] = ar[j];
            }
            __syncthreads();
            if (tid < K) {
                float xx1 = fmaxf(jb[0], myx1), yy1 = fmaxf(jb[1], myy1);
                float xx2 = fminf(jb[2], myx2), yy2 = fminf(jb[3], myy2);
                float iw = fmaxf(0.0f, __fadd_rn(__fsub_rn(xx2, xx1), 1.0f));
                float ih = fmaxf(0.0f, __fadd_rn(__fsub_rn(yy2, yy1), 1.0f));
                float inter = __fmul_rn(iw, ih);
                float uni = __fsub_rn(__fadd_rn(jb[4], mya), inter);  // areas[j]+areas-inter
                float iou = __fdiv_rn(inter, uni);
                if (iou > 0.7f || (u32)tid == j) act[tid] = 0;
            }
            ++nk;
        }
        __syncthreads();
    }
    if (tid == 0) *a.nkeep[l] = nk;
}

// ============ L4: emit per-level padded proposals (f32) =====================
struct EArgs {
    const float* ts[5];
    const float* boxes[5];
    const int* keep[5];
    const int* nkeep[5];
    float* ob;
    float* os;
};

__global__ __launch_bounds__(256) void k_emit(EArgs a) {
    int l = blockIdx.x;
    int nk = *a.nkeep[l];
    for (int r = threadIdx.x; r < 1000; r += 256) {
        float b0 = 0, b1 = 0, b2 = 0, b3 = 0, s = -1000000000.0f;
        if (r < nk) {
            int j = a.keep[l][r];
            const float* bp = &a.boxes[l][(size_t)j * 4];
            b0 = bp[0];
            b1 = bp[1];
            b2 = bp[2];
            b3 = bp[3];
            s = a.ts[l][j];
        }
        float* op = &a.ob[(size_t)(l * 1000 + r) * 4];
        op[0] = b0;
        op[1] = b1;
        op[2] = b2;
        op[3] = b3;
        a.os[l * 1000 + r] = s;
    }
}

// ============ L5: literal final top-1000 (f32 keys, lowest-idx ties) ========
__global__ __launch_bounds__(1024) void k_final_lit(const float* __restrict__ ob,
                                                    const float* __restrict__ os,
                                                    float* __restrict__ out) {
    __shared__ u64 taken[80];
    __shared__ float bv[1024];
    __shared__ u32 bi[1024];
    int tid = threadIdx.x;
    for (int i = tid; i < 80; i += 1024) taken[i] = 0ull;
    __syncthreads();
    for (int r = 0; r < 1000; ++r) {
        float best = -2.0e9f;
        u32 bidx = 0xFFFFFFFFu;
        for (int i = tid; i < 5000; i += 1024) {
            if (!((taken[i >> 6] >> (i & 63)) & 1ull)) {
                float v = os[i];
                if (v > best) { best = v; bidx = (u32)i; }
            }
        }
        bv[tid] = best;
        bi[tid] = bidx;
        __syncthreads();
        for (int ofs = 512; ofs > 0; ofs >>= 1) {
            if (tid < ofs) {
                float vo = bv[tid + ofs];
                u32 io = bi[tid + ofs];
                if (vo > bv[tid] || (vo == bv[tid] && io < bi[tid])) {
                    bv[tid] = vo;
                    bi[tid] = io;
                }
            }
            __syncthreads();
        }
        if (tid == 0) {
            u32 gi = bi[0];
            taken[gi >> 6] |= (1ull << (gi & 63));
            float s = os[gi];
            const float* b = &ob[(size_t)gi * 4];
            float x1 = b[0], y1 = b[1], x2 = b[2], y2 = b[3];
            out[r * 4 + 0] = x1;
            out[r * 4 + 1] = y1;
            out[r * 4 + 2] = x2;
            out[r * 4 + 3] = y2;
            out[4000 + r] = s;
            float area = __fmul_rn(__fadd_rn(__fsub_rn(x2, x1), 1.0f),
                                   __fadd_rn(__fsub_rn(y2, y1), 1.0f));
            float scale = __fsqrt_rn(fmaxf(area, 1.0f));
            float t = __fadd_rn(__fdiv_rn(scale, 224.0f), 1e-6f);
            float lv = floorf(__fadd_rn(4.0f, log2f(t)));
            lv = fminf(fmaxf(lv, 2.0f), 5.0f);
            out[5000 + r] = lv;
        }
        __syncthreads();
    }
}

// ============ host ==========================================================
extern "C" void kernel_launch(void* const* d_in, const int* in_sizes, int n_in,
                              void* d_out, int out_size, void* d_ws, size_t ws_size,
                              hipStream_t stream) {
    const float *fp2 = nullptr, *fp3 = nullptr, *fp4 = nullptr, *fp5 = nullptr, *fp6 = nullptr;
    const float *im_info = nullptr, *conv_w = nullptr, *conv_b = nullptr;
    const float *cls_w = nullptr, *cls_b = nullptr, *bbox_w = nullptr, *bbox_b = nullptr;
    for (int i = 0; i < n_in; ++i) {
        const float* p = (const float*)d_in[i];
        switch (in_sizes[i]) {
            case 16777216: fp2 = p; break;
            case 4194304: fp3 = p; break;
            case 1048576: fp4 = p; break;
            case 262144: fp5 = p; break;
            case 65536: fp6 = p; break;
            case 3: im_info = p; break;
            case 589824: conv_w = p; break;
            case 256: conv_b = p; break;
            case 1536: cls_w = p; break;
            case 6: cls_b = p; break;
            case 3072: bbox_w = p; break;
            case 12: bbox_b = p; break;
            default: break;
        }
    }
    const float* feats[5] = {fp2, fp3, fp4, fp5, fp6};  // levels 2..6

    size_t off = 0;
    auto take = [&](size_t bytes) -> void* {
        void* p = (char*)d_ws + off;
        off += (bytes + 255) & ~(size_t)255;
        return p;
    };
    int Hs[5] = {256, 128, 64, 32, 16};
    float* scores[5];
    float* deltas[5];
    float* ts[5];
    int* ti[5];
    float* boxes[5];
    float* areas[5];
    int* keep[5];
    int* nkeep[5];
    int Narr[5], Karr[5];
    for (int s = 0; s < 5; ++s) {
        int H = Hs[s];
        int N = 3 * H * H;
        Narr[s] = N;
        Karr[s] = N < 1000 ? N : 1000;
        scores[s] = (float*)take((size_t)N * 4);
        deltas[s] = (float*)take((size_t)N * 16);
        ts[s] = (float*)take(1024 * 4);
        ti[s] = (int*)take(1024 * 4);
        boxes[s] = (float*)take(1024 * 16);
        areas[s] = (float*)take(1024 * 4);
        keep[s] = (int*)take(1024 * 4);
        nkeep[s] = (int*)take(256);
    }
    float* ob = (float*)take((size_t)5000 * 16);
    float* os = (float*)take((size_t)5000 * 4);

    // base anchors: exact numpy semantics in f64, materialized f32 (lossless)
    double anc[5][12];
    for (int s = 0; s < 5; ++s) {
        int lvl = 2 + s;
        double stride = (double)(1 << lvl);
        double xc = 0.5 * (stride - 1.0);
        const double ratios[3] = {0.5, 1.0, 2.0};
        for (int rr = 0; rr < 3; ++rr) {
            double wsv = rint(sqrt(stride * stride / ratios[rr]));
            double hsv = rint(wsv * ratios[rr]);
            double WS = wsv * 8.0, HS = hsv * 8.0;
            anc[s][rr * 4 + 0] = xc - 0.5 * (WS - 1.0);
            anc[s][rr * 4 + 1] = xc - 0.5 * (HS - 1.0);
            anc[s][rr * 4 + 2] = xc + 0.5 * (WS - 1.0);
            anc[s][rr * 4 + 3] = xc + 0.5 * (HS - 1.0);
        }
    }

    for (int s = 0; s < 5; ++s) {
        int H = Hs[s];
        k_conv_lit<<<dim3(H * H), dim3(256), 0, stream>>>(
            feats[s], conv_w, conv_b, cls_w, cls_b, bbox_w, bbox_b,
            scores[s], deltas[s], H, H);
    }

    TArgs a2;
    NArgs a3;
    EArgs a4;
    for (int s = 0; s < 5; ++s) {
        a2.sc[s] = scores[s];
        a2.dl[s] = deltas[s];
        a2.ts[s] = ts[s];
        a2.ti[s] = ti[s];
        a2.boxes[s] = boxes[s];
        a2.areas[s] = areas[s];
        a2.N[s] = Narr[s];
        a2.K[s] = Karr[s];
        a2.W[s] = Hs[s];
        a2.stride[s] = (float)(1 << (2 + s));
        for (int q = 0; q < 12; ++q) a2.anc[s][q] = (float)anc[s][q];
        a3.ts[s] = ts[s];
        a3.boxes[s] = boxes[s];
        a3.areas[s] = areas[s];
        a3.K[s] = Karr[s];
        a3.keep[s] = keep[s];
        a3.nkeep[s] = nkeep[s];
        a4.ts[s] = ts[s];
        a4.boxes[s] = boxes[s];
        a4.keep[s] = keep[s];
        a4.nkeep[s] = nkeep[s];
    }
    a2.im_info = im_info;
    a4.ob = ob;
    a4.os = os;

    k_topk_lit<<<dim3(5), dim3(1024), 0, stream>>>(a2);
    k_nms_lit<<<dim3(5), dim3(1024), 0, stream>>>(a3);
    k_emit<<<dim3(5), dim3(256), 0, stream>>>(a4);
    k_final_lit<<<dim3(1), dim3(1024), 0, stream>>>(ob, os, (float*)d_out);
}

// Round 12
// 10224.480 us; speedup vs baseline: 3.1022x; 3.1022x over previous
//
#include <hip/hip_runtime.h>
#include <math.h>
#include <stdint.h>

typedef unsigned long long u64;
typedef unsigned int u32;

// ---------------- weight transpose: wT[(ci*9+d)*256 + oc] = w[oc][ci][d] ----
__global__ __launch_bounds__(256) void k_transpose_w(const float* __restrict__ w,
                                                     float* __restrict__ wT) {
    int t = blockIdx.x * 256 + threadIdx.x;
    if (t >= 2304 * 256) return;
    int kidx = t >> 8;
    int oc = t & 255;
    wT[t] = w[oc * 2304 + kidx];
}

// ======== L1: conv3x3(256->256, f64 acc) + relu + 1x1 heads, 16 pos/block ===
// 256 threads = 256 output channels; 16 consecutive positions in one row.
// f64 accumulation order per output is IDENTICAL to the verified r11 kernel:
// flat k = (ci*9 + ky*3 + kx) ascending.
__global__ __launch_bounds__(256, 2) void k_conv_heads(
    const float* __restrict__ x, const float* __restrict__ wT,
    const float* __restrict__ cb, const float* __restrict__ clsw,
    const float* __restrict__ clsb, const float* __restrict__ bbw,
    const float* __restrict__ bbb, float* __restrict__ scores,
    float* __restrict__ deltas, int H, int W) {
    __shared__ __align__(16) float xs[64][3][20];  // 15360 B
    __shared__ double hs[256][17];                 // 34816 B
    __shared__ float hw[18 * 256];                 // 18432 B
    __shared__ double hout[18][16];                // 2304 B

    int tid = threadIdx.x;
    int pos0 = blockIdx.x * 16;
    int row = pos0 / W;
    int col0 = pos0 % W;

    for (int t = tid; t < 6 * 256; t += 256) hw[t] = clsw[t];
    for (int t = tid; t < 12 * 256; t += 256) hw[1536 + t] = bbw[t];

    double acc[16];
#pragma unroll
    for (int p = 0; p < 16; ++p) acc[p] = 0.0;

    for (int cc = 0; cc < 4; ++cc) {
        __syncthreads();
        for (int t = tid; t < 64 * 3 * 20; t += 256) {
            int a = t / 60;
            int r = t % 60;
            int dy = r / 20;
            int dxx = r % 20;
            float v = 0.f;
            int gy = row - 1 + dy;
            int gx = col0 - 1 + dxx;
            if (dxx < 18 && gy >= 0 && gy < H && gx >= 0 && gx < W)
                v = x[((size_t)(cc * 64 + a) * H + gy) * W + gx];
            xs[a][dy][dxx] = v;
        }
        __syncthreads();
        int oc = tid;
        for (int a = 0; a < 64; ++a) {
#pragma unroll
            for (int dy = 0; dy < 3; ++dy) {
                double xr[18];
#pragma unroll
                for (int q = 0; q < 18; ++q) xr[q] = (double)xs[a][dy][q];
                const float* wrow = &wT[((size_t)(cc * 64 + a) * 9 + dy * 3) * 256 + oc];
                double w0 = (double)wrow[0];
                double w1 = (double)wrow[256];
                double w2 = (double)wrow[512];
#pragma unroll
                for (int p = 0; p < 16; ++p) {
                    acc[p] = fma(w0, xr[p], acc[p]);
                    acc[p] = fma(w1, xr[p + 1], acc[p]);
                    acc[p] = fma(w2, xr[p + 2], acc[p]);
                }
            }
        }
    }
    __syncthreads();
    {
        double bias = (double)cb[tid];
#pragma unroll
        for (int p = 0; p < 16; ++p) hs[tid][p] = fmax(acc[p] + bias, 0.0);
    }
    __syncthreads();
    for (int t = tid; t < 288; t += 256) {
        int p = t & 15, ch = t >> 4;
        double s = (ch < 6) ? (double)clsb[ch] : (double)bbb[ch - 6];
        const float* wv = &hw[ch * 256];
        for (int ci = 0; ci < 256; ++ci) s += (double)wv[ci] * hs[ci][p];
        hout[ch][p] = s;
    }
    __syncthreads();
    // f32 softmax with max-subtraction (verbatim r11 semantics)
    for (int t = tid; t < 48; t += 256) {
        int p = t & 15, a = t >> 4;
        int posi = pos0 + p;
        float c0 = (float)hout[a][p], c1 = (float)hout[3 + a][p];
        float m = fmaxf(c0, c1);
        float e0 = expf(__fsub_rn(c0, m));
        float e1 = expf(__fsub_rn(c1, m));
        scores[(size_t)posi * 3 + a] = __fdiv_rn(e1, __fadd_rn(e0, e1));
    }
    for (int t = tid; t < 192; t += 256) {
        int p = t & 15, j = t >> 4;
        int posi = pos0 + p;
        int a = j >> 2, c = j & 3;
        deltas[((size_t)posi * 3 + a) * 4 + c] = (float)hout[6 + j][p];
    }
}

// ============ L2: per-level top-k (argmax removal, f32 keys) + f32 decode ===
struct TArgs {
    const float* sc[5];
    const float* dl[5];
    float* ts[5];
    int* ti[5];
    float* boxes[5];
    float* areas[5];
    int N[5], K[5], W[5];
    float stride[5];
    float anc[5][12];
    const float* im_info;
};

__global__ __launch_bounds__(1024) void k_topk_lit(TArgs a) {
    __shared__ u64 taken[3072];
    __shared__ float cbv[1024];
    __shared__ u32 cbi[1024];
    __shared__ float bv[1024];
    __shared__ u32 bi[1024];
    int l = blockIdx.x;
    const float* sc = a.sc[l];
    int N = a.N[l], K = a.K[l];
    int tid = threadIdx.x;
    int nw = (N + 63) >> 6;
    for (int i = tid; i < nw; i += 1024) taken[i] = 0ull;
    {
        float best = -1.0f;
        u32 bidx = 0xFFFFFFFFu;
        for (int i = tid; i < N; i += 1024) {
            float v = sc[i];
            if (v > best) { best = v; bidx = (u32)i; }
        }
        cbv[tid] = best;
        cbi[tid] = bidx;
    }
    __syncthreads();
    for (int r = 0; r < K; ++r) {
        bv[tid] = cbv[tid];
        bi[tid] = cbi[tid];
        __syncthreads();
        for (int ofs = 512; ofs > 0; ofs >>= 1) {
            if (tid < ofs) {
                float vo = bv[tid + ofs];
                u32 io = bi[tid + ofs];
                if (vo > bv[tid] || (vo == bv[tid] && io < bi[tid])) {
                    bv[tid] = vo;
                    bi[tid] = io;
                }
            }
            __syncthreads();
        }
        u32 j = bi[0];
        if (tid == 0) {
            a.ts[l][r] = bv[0];
            a.ti[l][r] = (int)j;
            taken[j >> 6] |= (1ull << (j & 63));
        }
        __syncthreads();
        u32 o = j & 1023u;
        {
            u32 i = o + ((u32)tid << 10);
            float v2 = -1.0f;
            u32 i2 = 0xFFFFFFFFu;
            if (i < (u32)N && !((taken[i >> 6] >> (i & 63)) & 1ull)) {
                v2 = sc[i];
                i2 = i;
            }
            bv[tid] = v2;
            bi[tid] = i2;
        }
        __syncthreads();
        for (int ofs = 512; ofs > 0; ofs >>= 1) {
            if (tid < ofs) {
                float vo = bv[tid + ofs];
                u32 io = bi[tid + ofs];
                if (vo > bv[tid] || (vo == bv[tid] && io < bi[tid])) {
                    bv[tid] = vo;
                    bi[tid] = io;
                }
            }
            __syncthreads();
        }
        if (tid == 0) {
            cbv[o] = bv[0];
            cbi[o] = bi[0];
        }
        __syncthreads();
    }
    float imh = a.im_info[0], imw = a.im_info[1];
    float hi_x = __fsub_rn(imw, 1.0f), hi_y = __fsub_rn(imh, 1.0f);
    if (tid < K) {
        int idx = a.ti[l][tid];
        int aidx = idx % 3;
        int posi = idx / 3;
        int W = a.W[l];
        int rr = posi / W, cc = posi % W;
        float sx = __fmul_rn((float)cc, a.stride[l]);
        float sy = __fmul_rn((float)rr, a.stride[l]);
        const float* an = &a.anc[l][aidx * 4];
        float ax1 = __fadd_rn(an[0], sx), ay1 = __fadd_rn(an[1], sy);
        float ax2 = __fadd_rn(an[2], sx), ay2 = __fadd_rn(an[3], sy);
        float w = __fadd_rn(__fsub_rn(ax2, ax1), 1.0f);
        float h = __fadd_rn(__fsub_rn(ay2, ay1), 1.0f);
        float cx = __fadd_rn(ax1, __fmul_rn(0.5f, w));
        float cy = __fadd_rn(ay1, __fmul_rn(0.5f, h));
        const float* d = &a.dl[l][(size_t)idx * 4];
        float dx = d[0], dy = d[1];
        float dw = fminf(d[2], 4.135166556742356f);
        float dh = fminf(d[3], 4.135166556742356f);
        float pcx = __fadd_rn(__fmul_rn(dx, w), cx);
        float pcy = __fadd_rn(__fmul_rn(dy, h), cy);
        float pw = __fmul_rn(expf(dw), w);
        float ph = __fmul_rn(expf(dh), h);
        float hw2 = __fmul_rn(0.5f, pw), hh2 = __fmul_rn(0.5f, ph);
        float x1 = __fsub_rn(pcx, hw2);
        float y1 = __fsub_rn(pcy, hh2);
        float x2 = __fsub_rn(__fadd_rn(pcx, hw2), 1.0f);
        float y2 = __fsub_rn(__fadd_rn(pcy, hh2), 1.0f);
        x1 = fminf(fmaxf(x1, 0.0f), hi_x);
        y1 = fminf(fmaxf(y1, 0.0f), hi_y);
        x2 = fminf(fmaxf(x2, 0.0f), hi_x);
        y2 = fminf(fmaxf(y2, 0.0f), hi_y);
        float* obx = &a.boxes[l][(size_t)tid * 4];
        obx[0] = x1;
        obx[1] = y1;
        obx[2] = x2;
        obx[3] = y2;
        a.areas[l][tid] = __fmul_rn(__fadd_rn(__fsub_rn(x2, x1), 1.0f),
                                    __fadd_rn(__fsub_rn(y2, y1), 1.0f));
    }
}

// ============ L3: literal NMS (f32 IoU) =====================================
struct NArgs {
    const float* ts[5];
    const float* boxes[5];
    const float* areas[5];
    int K[5];
    int* keep[5];
    int* nkeep[5];
};

__global__ __launch_bounds__(1024) void k_nms_lit(NArgs a) {
    __shared__ float bv[1024];
    __shared__ u32 bi[1024];
    __shared__ unsigned char act[1024];
    __shared__ float jb[5];
    int l = blockIdx.x;
    int K = a.K[l];
    const float* ts = a.ts[l];
    const float* bx = a.boxes[l];
    const float* ar = a.areas[l];
    int tid = threadIdx.x;
    act[tid] = (tid < K) ? 1 : 0;
    float myx1 = 0, myy1 = 0, myx2 = 0, myy2 = 0, mya = 0, mys = 0;
    if (tid < K) {
        myx1 = bx[tid * 4];
        myy1 = bx[tid * 4 + 1];
        myx2 = bx[tid * 4 + 2];
        myy2 = bx[tid * 4 + 3];
        mya = ar[tid];
        mys = ts[tid];
    }
    __syncthreads();
    int nk = 0;
    for (int it = 0; it < K; ++it) {
        bv[tid] = (tid < K && act[tid]) ? mys : -1.0f;
        bi[tid] = (tid < K && act[tid]) ? (u32)tid : 0xFFFFFFFFu;
        __syncthreads();
        for (int ofs = 512; ofs > 0; ofs >>= 1) {
            if (tid < ofs) {
                float vo = bv[tid + ofs];
                u32 io = bi[tid + ofs];
                if (vo > bv[tid] || (vo == bv[tid] && io < bi[tid])) {
                    bv[tid] = vo;
                    bi[tid] = io;
                }
            }
            __syncthreads();
        }
        u32 j = bi[0];
        bool valid = (j != 0xFFFFFFFFu);
        if (tid == 0) a.keep[l][it] = valid ? (int)j : -1;
        if (valid) {
            if (tid == 0) {
                jb[0] = bx[j * 4];
                jb[1] = bx[j * 4 + 1];
                jb[2] = bx[j * 4 + 2];
                jb[3] = bx[j * 4 + 3];
                jb[4] = ar[j];
            }
            __syncthreads();
            if (tid < K) {
                float xx1 = fmaxf(jb[0], myx1), yy1 = fmaxf(jb[1], myy1);
                float xx2 = fminf(jb[2], myx2), yy2 = fminf(jb[3], myy2);
                float iw = fmaxf(0.0f, __fadd_rn(__fsub_rn(xx2, xx1), 1.0f));
                float ih = fmaxf(0.0f, __fadd_rn(__fsub_rn(yy2, yy1), 1.0f));
                float inter = __fmul_rn(iw, ih);
                float uni = __fsub_rn(__fadd_rn(jb[4], mya), inter);
                float iou = __fdiv_rn(inter, uni);
                if (iou > 0.7f || (u32)tid == j) act[tid] = 0;
            }
            ++nk;
        }
        __syncthreads();
    }
    if (tid == 0) *a.nkeep[l] = nk;
}

// ============ L4: emit per-level padded proposals (f32) =====================
struct EArgs {
    const float* ts[5];
    const float* boxes[5];
    const int* keep[5];
    const int* nkeep[5];
    float* ob;
    float* os;
};

__global__ __launch_bounds__(256) void k_emit(EArgs a) {
    int l = blockIdx.x;
    int nk = *a.nkeep[l];
    for (int r = threadIdx.x; r < 1000; r += 256) {
        float b0 = 0, b1 = 0, b2 = 0, b3 = 0, s = -1000000000.0f;
        if (r < nk) {
            int j = a.keep[l][r];
            const float* bp = &a.boxes[l][(size_t)j * 4];
            b0 = bp[0];
            b1 = bp[1];
            b2 = bp[2];
            b3 = bp[3];
            s = a.ts[l][j];
        }
        float* op = &a.ob[(size_t)(l * 1000 + r) * 4];
        op[0] = b0;
        op[1] = b1;
        op[2] = b2;
        op[3] = b3;
        a.os[l * 1000 + r] = s;
    }
}

// ============ L5: literal final top-1000 (f32 keys, lowest-idx ties) ========
__global__ __launch_bounds__(1024) void k_final_lit(const float* __restrict__ ob,
                                                    const float* __restrict__ os,
                                                    float* __restrict__ out) {
    __shared__ u64 taken[80];
    __shared__ float bv[1024];
    __shared__ u32 bi[1024];
    int tid = threadIdx.x;
    for (int i = tid; i < 80; i += 1024) taken[i] = 0ull;
    __syncthreads();
    for (int r = 0; r < 1000; ++r) {
        float best = -2.0e9f;
        u32 bidx = 0xFFFFFFFFu;
        for (int i = tid; i < 5000; i += 1024) {
            if (!((taken[i >> 6] >> (i & 63)) & 1ull)) {
                float v = os[i];
                if (v > best) { best = v; bidx = (u32)i; }
            }
        }
        bv[tid] = best;
        bi[tid] = bidx;
        __syncthreads();
        for (int ofs = 512; ofs > 0; ofs >>= 1) {
            if (tid < ofs) {
                float vo = bv[tid + ofs];
                u32 io = bi[tid + ofs];
                if (vo > bv[tid] || (vo == bv[tid] && io < bi[tid])) {
                    bv[tid] = vo;
                    bi[tid] = io;
                }
            }
            __syncthreads();
        }
        if (tid == 0) {
            u32 gi = bi[0];
            taken[gi >> 6] |= (1ull << (gi & 63));
            float s = os[gi];
            const float* b = &ob[(size_t)gi * 4];
            float x1 = b[0], y1 = b[1], x2 = b[2], y2 = b[3];
            out[r * 4 + 0] = x1;
            out[r * 4 + 1] = y1;
            out[r * 4 + 2] = x2;
            out[r * 4 + 3] = y2;
            out[4000 + r] = s;
            float area = __fmul_rn(__fadd_rn(__fsub_rn(x2, x1), 1.0f),
                                   __fadd_rn(__fsub_rn(y2, y1), 1.0f));
            float scale = __fsqrt_rn(fmaxf(area, 1.0f));
            float t = __fadd_rn(__fdiv_rn(scale, 224.0f), 1e-6f);
            float lv = floorf(__fadd_rn(4.0f, log2f(t)));
            lv = fminf(fmaxf(lv, 2.0f), 5.0f);
            out[5000 + r] = lv;
        }
        __syncthreads();
    }
}

// ============ host ==========================================================
extern "C" void kernel_launch(void* const* d_in, const int* in_sizes, int n_in,
                              void* d_out, int out_size, void* d_ws, size_t ws_size,
                              hipStream_t stream) {
    const float *fp2 = nullptr, *fp3 = nullptr, *fp4 = nullptr, *fp5 = nullptr, *fp6 = nullptr;
    const float *im_info = nullptr, *conv_w = nullptr, *conv_b = nullptr;
    const float *cls_w = nullptr, *cls_b = nullptr, *bbox_w = nullptr, *bbox_b = nullptr;
    for (int i = 0; i < n_in; ++i) {
        const float* p = (const float*)d_in[i];
        switch (in_sizes[i]) {
            case 16777216: fp2 = p; break;
            case 4194304: fp3 = p; break;
            case 1048576: fp4 = p; break;
            case 262144: fp5 = p; break;
            case 65536: fp6 = p; break;
            case 3: im_info = p; break;
            case 589824: conv_w = p; break;
            case 256: conv_b = p; break;
            case 1536: cls_w = p; break;
            case 6: cls_b = p; break;
            case 3072: bbox_w = p; break;
            case 12: bbox_b = p; break;
            default: break;
        }
    }
    const float* feats[5] = {fp2, fp3, fp4, fp5, fp6};  // levels 2..6

    size_t off = 0;
    auto take = [&](size_t bytes) -> void* {
        void* p = (char*)d_ws + off;
        off += (bytes + 255) & ~(size_t)255;
        return p;
    };
    float* wT = (float*)take((size_t)2304 * 256 * 4);
    int Hs[5] = {256, 128, 64, 32, 16};
    float* scores[5];
    float* deltas[5];
    float* ts[5];
    int* ti[5];
    float* boxes[5];
    float* areas[5];
    int* keep[5];
    int* nkeep[5];
    int Narr[5], Karr[5];
    for (int s = 0; s < 5; ++s) {
        int H = Hs[s];
        int N = 3 * H * H;
        Narr[s] = N;
        Karr[s] = N < 1000 ? N : 1000;
        scores[s] = (float*)take((size_t)N * 4);
        deltas[s] = (float*)take((size_t)N * 16);
        ts[s] = (float*)take(1024 * 4);
        ti[s] = (int*)take(1024 * 4);
        boxes[s] = (float*)take(1024 * 16);
        areas[s] = (float*)take(1024 * 4);
        keep[s] = (int*)take(1024 * 4);
        nkeep[s] = (int*)take(256);
    }
    float* ob = (float*)take((size_t)5000 * 16);
    float* os = (float*)take((size_t)5000 * 4);

    double anc[5][12];
    for (int s = 0; s < 5; ++s) {
        int lvl = 2 + s;
        double stride = (double)(1 << lvl);
        double xc = 0.5 * (stride - 1.0);
        const double ratios[3] = {0.5, 1.0, 2.0};
        for (int rr = 0; rr < 3; ++rr) {
            double wsv = rint(sqrt(stride * stride / ratios[rr]));
            double hsv = rint(wsv * ratios[rr]);
            double WS = wsv * 8.0, HS = hsv * 8.0;
            anc[s][rr * 4 + 0] = xc - 0.5 * (WS - 1.0);
            anc[s][rr * 4 + 1] = xc - 0.5 * (HS - 1.0);
            anc[s][rr * 4 + 2] = xc + 0.5 * (WS - 1.0);
            anc[s][rr * 4 + 3] = xc + 0.5 * (HS - 1.0);
        }
    }

    k_transpose_w<<<dim3(2304), dim3(256), 0, stream>>>(conv_w, wT);
    for (int s = 0; s < 5; ++s) {
        int H = Hs[s];
        k_conv_heads<<<dim3(H * H / 16), dim3(256), 0, stream>>>(
            feats[s], wT, conv_b, cls_w, cls_b, bbox_w, bbox_b,
            scores[s], deltas[s], H, H);
    }

    TArgs a2;
    NArgs a3;
    EArgs a4;
    for (int s = 0; s < 5; ++s) {
        a2.sc[s] = scores[s];
        a2.dl[s] = deltas[s];
        a2.ts[s] = ts[s];
        a2.ti[s] = ti[s];
        a2.boxes[s] = boxes[s];
        a2.areas[s] = areas[s];
        a2.N[s] = Narr[s];
        a2.K[s] = Karr[s];
        a2.W[s] = Hs[s];
        a2.stride[s] = (float)(1 << (2 + s));
        for (int q = 0; q < 12; ++q) a2.anc[s][q] = (float)anc[s][q];
        a3.ts[s] = ts[s];
        a3.boxes[s] = boxes[s];
        a3.areas[s] = areas[s];
        a3.K[s] = Karr[s];
        a3.keep[s] = keep[s];
        a3.nkeep[s] = nkeep[s];
        a4.ts[s] = ts[s];
        a4.boxes[s] = boxes[s];
        a4.keep[s] = keep[s];
        a4.nkeep[s] = nkeep[s];
    }
    a2.im_info = im_info;
    a4.ob = ob;
    a4.os = os;

    k_topk_lit<<<dim3(5), dim3(1024), 0, stream>>>(a2);
    k_nms_lit<<<dim3(5), dim3(1024), 0, stream>>>(a3);
    k_emit<<<dim3(5), dim3(256), 0, stream>>>(a4);
    k_final_lit<<<dim3(1), dim3(1024), 0, stream>>>(ob, os, (float*)d_out);
}

// Round 13
// 5087.484 us; speedup vs baseline: 6.2346x; 2.0097x over previous
//
#include <hip/hip_runtime.h>
#include <math.h>
#include <stdint.h>

typedef unsigned long long u64;
typedef unsigned int u32;

#define CAP 4096
#define NTOT 261888  // 196608+49152+12288+3072+768

__device__ __forceinline__ u32 fkey32(float f) {
    u32 u = __float_as_uint(f);
    return (u & 0x80000000u) ? ~u : (u | 0x80000000u);
}

// ---------------- weight transpose ------------------------------------------
__global__ __launch_bounds__(256) void k_transpose_w(const float* __restrict__ w,
                                                     float* __restrict__ wT) {
    int t = blockIdx.x * 256 + threadIdx.x;
    if (t >= 2304 * 256) return;
    int kidx = t >> 8;
    int oc = t & 255;
    wT[t] = w[oc * 2304 + kidx];
}

// ======== L1: conv3x3(256->256, f64 acc) + relu + heads (verbatim r12) ======
__global__ __launch_bounds__(256, 2) void k_conv_heads(
    const float* __restrict__ x, const float* __restrict__ wT,
    const float* __restrict__ cb, const float* __restrict__ clsw,
    const float* __restrict__ clsb, const float* __restrict__ bbw,
    const float* __restrict__ bbb, float* __restrict__ scores,
    float* __restrict__ deltas, int H, int W) {
    __shared__ __align__(16) float xs[64][3][20];
    __shared__ double hs[256][17];
    __shared__ float hw[18 * 256];
    __shared__ double hout[18][16];

    int tid = threadIdx.x;
    int pos0 = blockIdx.x * 16;
    int row = pos0 / W;
    int col0 = pos0 % W;

    for (int t = tid; t < 6 * 256; t += 256) hw[t] = clsw[t];
    for (int t = tid; t < 12 * 256; t += 256) hw[1536 + t] = bbw[t];

    double acc[16];
#pragma unroll
    for (int p = 0; p < 16; ++p) acc[p] = 0.0;

    for (int cc = 0; cc < 4; ++cc) {
        __syncthreads();
        for (int t = tid; t < 64 * 3 * 20; t += 256) {
            int a = t / 60;
            int r = t % 60;
            int dy = r / 20;
            int dxx = r % 20;
            float v = 0.f;
            int gy = row - 1 + dy;
            int gx = col0 - 1 + dxx;
            if (dxx < 18 && gy >= 0 && gy < H && gx >= 0 && gx < W)
                v = x[((size_t)(cc * 64 + a) * H + gy) * W + gx];
            xs[a][dy][dxx] = v;
        }
        __syncthreads();
        int oc = tid;
        for (int a = 0; a < 64; ++a) {
#pragma unroll
            for (int dy = 0; dy < 3; ++dy) {
                double xr[18];
#pragma unroll
                for (int q = 0; q < 18; ++q) xr[q] = (double)xs[a][dy][q];
                const float* wrow = &wT[((size_t)(cc * 64 + a) * 9 + dy * 3) * 256 + oc];
                double w0 = (double)wrow[0];
                double w1 = (double)wrow[256];
                double w2 = (double)wrow[512];
#pragma unroll
                for (int p = 0; p < 16; ++p) {
                    acc[p] = fma(w0, xr[p], acc[p]);
                    acc[p] = fma(w1, xr[p + 1], acc[p]);
                    acc[p] = fma(w2, xr[p + 2], acc[p]);
                }
            }
        }
    }
    __syncthreads();
    {
        double bias = (double)cb[tid];
#pragma unroll
        for (int p = 0; p < 16; ++p) hs[tid][p] = fmax(acc[p] + bias, 0.0);
    }
    __syncthreads();
    for (int t = tid; t < 288; t += 256) {
        int p = t & 15, ch = t >> 4;
        double s = (ch < 6) ? (double)clsb[ch] : (double)bbb[ch - 6];
        const float* wv = &hw[ch * 256];
        for (int ci = 0; ci < 256; ++ci) s += (double)wv[ci] * hs[ci][p];
        hout[ch][p] = s;
    }
    __syncthreads();
    for (int t = tid; t < 48; t += 256) {
        int p = t & 15, a = t >> 4;
        int posi = pos0 + p;
        float c0 = (float)hout[a][p], c1 = (float)hout[3 + a][p];
        float m = fmaxf(c0, c1);
        float e0 = expf(__fsub_rn(c0, m));
        float e1 = expf(__fsub_rn(c1, m));
        scores[(size_t)posi * 3 + a] = __fdiv_rn(e1, __fadd_rn(e0, e1));
    }
    for (int t = tid; t < 192; t += 256) {
        int p = t & 15, j = t >> 4;
        int posi = pos0 + p;
        int a = j >> 2, c = j & 3;
        deltas[((size_t)posi * 3 + a) * 4 + c] = (float)hout[6 + j][p];
    }
}

// ============ top-K selection machinery =====================================
struct SelArgs {
    const float* sc[5];
    u32* h12;      // [5*4096]
    u32* h24;      // [5*4096]
    u32* h8;       // [5*256]
    u32* selst;    // [5*4]: 0=bin12,1=want12,2=prefix24,3=want24
    u32* T32;      // [5]
    u64* cand;     // [5*CAP]
    u32* ccnt;     // [5]
    int N[5], K[5];
    int needT[5];
};

__device__ __forceinline__ void lvl_lookup(int g, int& l, int& base) {
    if (g < 196608) { l = 0; base = 0; }
    else if (g < 245760) { l = 1; base = 196608; }
    else if (g < 258048) { l = 2; base = 245760; }
    else if (g < 261120) { l = 3; base = 258048; }
    else { l = 4; base = 261120; }
}

__global__ __launch_bounds__(256) void k_zero(SelArgs a) {
    int g = blockIdx.x * 256 + threadIdx.x;
    if (g < 5 * 4096) { a.h12[g] = 0; a.h24[g] = 0; }
    if (g < 5 * 256) a.h8[g] = 0;
    if (g < 5) a.ccnt[g] = 0;
}

__global__ __launch_bounds__(256) void k_h12(SelArgs a) {
    int g = blockIdx.x * 256 + threadIdx.x;
    if (g >= NTOT) return;
    int l, base;
    lvl_lookup(g, l, base);
    if (!a.needT[l]) return;
    u32 key = __float_as_uint(a.sc[l][g - base]);  // scores > 0: bits monotonic
    atomicAdd(&a.h12[l * 4096 + (key >> 20)], 1u);
}

__global__ __launch_bounds__(1024) void k_sel12(SelArgs a) {
    __shared__ u32 h[4096];
    int l = blockIdx.x;
    if (!a.needT[l]) return;
    for (int i = threadIdx.x; i < 4096; i += 1024) h[i] = a.h12[l * 4096 + i];
    __syncthreads();
    if (threadIdx.x == 0) {
        u32 K = (u32)a.K[l], c = 0;
        for (int b = 4095; b >= 0; --b) {
            c += h[b];
            if (c >= K) {
                a.selst[l * 4 + 0] = (u32)b;
                a.selst[l * 4 + 1] = K - (c - h[b]);
                break;
            }
        }
    }
}

__global__ __launch_bounds__(256) void k_h24(SelArgs a) {
    int g = blockIdx.x * 256 + threadIdx.x;
    if (g >= NTOT) return;
    int l, base;
    lvl_lookup(g, l, base);
    if (!a.needT[l]) return;
    u32 key = __float_as_uint(a.sc[l][g - base]);
    if ((key >> 20) == a.selst[l * 4 + 0])
        atomicAdd(&a.h24[l * 4096 + ((key >> 8) & 0xFFFu)], 1u);
}

__global__ __launch_bounds__(1024) void k_sel24(SelArgs a) {
    __shared__ u32 h[4096];
    int l = blockIdx.x;
    if (!a.needT[l]) return;
    for (int i = threadIdx.x; i < 4096; i += 1024) h[i] = a.h24[l * 4096 + i];
    __syncthreads();
    if (threadIdx.x == 0) {
        u32 want = a.selst[l * 4 + 1], c = 0;
        for (int b = 4095; b >= 0; --b) {
            c += h[b];
            if (c >= want) {
                a.selst[l * 4 + 2] = (a.selst[l * 4 + 0] << 12) | (u32)b;
                a.selst[l * 4 + 3] = want - (c - h[b]);
                break;
            }
        }
    }
}

__global__ __launch_bounds__(256) void k_h8(SelArgs a) {
    int g = blockIdx.x * 256 + threadIdx.x;
    if (g >= NTOT) return;
    int l, base;
    lvl_lookup(g, l, base);
    if (!a.needT[l]) return;
    u32 key = __float_as_uint(a.sc[l][g - base]);
    if ((key >> 8) == a.selst[l * 4 + 2])
        atomicAdd(&a.h8[l * 256 + (key & 0xFFu)], 1u);
}

__global__ __launch_bounds__(256) void k_sel8(SelArgs a) {
    __shared__ u32 h[256];
    int l = blockIdx.x;
    if (!a.needT[l]) {
        if (threadIdx.x == 0) a.T32[l] = 0u;
        return;
    }
    if (threadIdx.x < 256) h[threadIdx.x] = a.h8[l * 256 + threadIdx.x];
    __syncthreads();
    if (threadIdx.x == 0) {
        u32 want = a.selst[l * 4 + 3], c = 0;
        for (int b = 255; b >= 0; --b) {
            c += h[b];
            if (c >= want) {
                a.T32[l] = (a.selst[l * 4 + 2] << 8) | (u32)b;
                break;
            }
        }
    }
}

__global__ __launch_bounds__(256) void k_compact(SelArgs a) {
    int g = blockIdx.x * 256 + threadIdx.x;
    if (g >= NTOT) return;
    int l, base;
    lvl_lookup(g, l, base);
    int i = g - base;
    u32 key = __float_as_uint(a.sc[l][i]);
    if (key >= a.T32[l]) {
        u32 p = atomicAdd(&a.ccnt[l], 1u);
        if (p < CAP) a.cand[l * CAP + p] = ((u64)key << 32) | (u32)(~(u32)i);
    }
}

// ============ L2b: sort candidates + decode (decode verbatim r12) ===========
struct TArgs {
    const u64* cand;
    const u32* ccnt;
    const float* dl[5];
    float* ts[5];
    float* boxes[5];
    float* areas[5];
    int K[5], W[5];
    float stride[5];
    float anc[5][12];
    const float* im_info;
};

__global__ __launch_bounds__(1024) void k_sortdecode(TArgs a) {
    __shared__ u64 sk[CAP];
    int l = blockIdx.x;
    int tid = threadIdx.x;
    u32 cnt = a.ccnt[l];
    if (cnt > CAP) cnt = CAP;
    for (int i = tid; i < CAP; i += 1024)
        sk[i] = (i < (int)cnt) ? a.cand[l * CAP + i] : 0ull;
    __syncthreads();
    for (int k2 = 2; k2 <= CAP; k2 <<= 1)
        for (int j = k2 >> 1; j > 0; j >>= 1) {
            for (int i = tid; i < CAP; i += 1024) {
                int p2 = i ^ j;
                if (p2 > i) {
                    u64 va = sk[i], vb = sk[p2];
                    if ((va < vb) == ((i & k2) == 0)) {
                        sk[i] = vb;
                        sk[p2] = va;
                    }
                }
            }
            __syncthreads();
        }
    int K = a.K[l];
    float imh = a.im_info[0], imw = a.im_info[1];
    float hi_x = __fsub_rn(imw, 1.0f), hi_y = __fsub_rn(imh, 1.0f);
    if (tid < K) {
        u64 v = sk[tid];
        u32 idx = ~(u32)(v & 0xffffffffu);
        float score = __uint_as_float((u32)(v >> 32));
        a.ts[l][tid] = score;
        int aidx = idx % 3;
        int posi = idx / 3;
        int W = a.W[l];
        int rr = posi / W, cc = posi % W;
        float sx = __fmul_rn((float)cc, a.stride[l]);
        float sy = __fmul_rn((float)rr, a.stride[l]);
        const float* an = &a.anc[l][aidx * 4];
        float ax1 = __fadd_rn(an[0], sx), ay1 = __fadd_rn(an[1], sy);
        float ax2 = __fadd_rn(an[2], sx), ay2 = __fadd_rn(an[3], sy);
        float w = __fadd_rn(__fsub_rn(ax2, ax1), 1.0f);
        float h = __fadd_rn(__fsub_rn(ay2, ay1), 1.0f);
        float cx = __fadd_rn(ax1, __fmul_rn(0.5f, w));
        float cy = __fadd_rn(ay1, __fmul_rn(0.5f, h));
        const float* d = &a.dl[l][(size_t)idx * 4];
        float dx = d[0], dy = d[1];
        float dw = fminf(d[2], 4.135166556742356f);
        float dh = fminf(d[3], 4.135166556742356f);
        float pcx = __fadd_rn(__fmul_rn(dx, w), cx);
        float pcy = __fadd_rn(__fmul_rn(dy, h), cy);
        float pw = __fmul_rn(expf(dw), w);
        float ph = __fmul_rn(expf(dh), h);
        float hw2 = __fmul_rn(0.5f, pw), hh2 = __fmul_rn(0.5f, ph);
        float x1 = __fsub_rn(pcx, hw2);
        float y1 = __fsub_rn(pcy, hh2);
        float x2 = __fsub_rn(__fadd_rn(pcx, hw2), 1.0f);
        float y2 = __fsub_rn(__fadd_rn(pcy, hh2), 1.0f);
        x1 = fminf(fmaxf(x1, 0.0f), hi_x);
        y1 = fminf(fmaxf(y1, 0.0f), hi_y);
        x2 = fminf(fmaxf(x2, 0.0f), hi_x);
        y2 = fminf(fmaxf(y2, 0.0f), hi_y);
        float* obx = &a.boxes[l][(size_t)tid * 4];
        obx[0] = x1;
        obx[1] = y1;
        obx[2] = x2;
        obx[3] = y2;
        a.areas[l][tid] = __fmul_rn(__fadd_rn(__fsub_rn(x2, x1), 1.0f),
                                    __fadd_rn(__fsub_rn(y2, y1), 1.0f));
    }
}

// ============ L3a: IoU suppression bit-matrix (f32 ops mirror r12 NMS) ======
struct IArgs {
    const float* boxes[5];
    const float* areas[5];
    u64* sup[5];
    int K[5];
};

__global__ __launch_bounds__(256) void k_iou(IArgs a) {
    int bx = blockIdx.x;
    int l = bx / 1000;
    int i = bx % 1000;
    int K = a.K[l];
    if (i >= K) return;
    const float* bi = &a.boxes[l][(size_t)i * 4];
    float x1 = bi[0], y1 = bi[1], x2 = bi[2], y2 = bi[3];
    float ai = a.areas[l][i];
    int lane = threadIdx.x & 63;
    int wv = threadIdx.x >> 6;
#pragma unroll
    for (int it = 0; it < 4; ++it) {
        int j = it * 256 + wv * 64 + lane;
        bool sup = false;
        if (j > i && j < K) {
            const float* bj = &a.boxes[l][(size_t)j * 4];
            float xx1 = fmaxf(x1, bj[0]);
            float yy1 = fmaxf(y1, bj[1]);
            float xx2 = fminf(x2, bj[2]);
            float yy2 = fminf(y2, bj[3]);
            float iw = fmaxf(0.0f, __fadd_rn(__fsub_rn(xx2, xx1), 1.0f));
            float ih = fmaxf(0.0f, __fadd_rn(__fsub_rn(yy2, yy1), 1.0f));
            float inter = __fmul_rn(iw, ih);
            float uni = __fsub_rn(__fadd_rn(ai, a.areas[l][j]), inter);
            float iou = __fdiv_rn(inter, uni);
            sup = iou > 0.7f;
        }
        u64 m = __ballot(sup);
        if (lane == 0) a.sup[l][(size_t)i * 16 + it * 4 + wv] = m;
    }
}

// ============ L3b: greedy NMS scan (1 wave/level, 16-row prefetch ring) =====
struct GArgs {
    const u64* sup[5];
    int K[5];
    int* keep[5];
    int* nkeep[5];
};

__global__ __launch_bounds__(64) void k_nms_scan(GArgs a) {
    int l = blockIdx.x;
    int K = a.K[l];
    const u64* __restrict__ sup = a.sup[l];
    int lane = threadIdx.x;
    bool owner = lane < 16;
    u64 mask = 0ull;
    int nk = 0;
    int* keep = a.keep[l];
    u64 r[16];
#pragma unroll
    for (int q = 0; q < 16; ++q)
        r[q] = (owner && q < K) ? sup[(size_t)q * 16 + lane] : 0ull;
    for (int i0 = 0; i0 < K; i0 += 16) {
#pragma unroll
        for (int q = 0; q < 16; ++q) {
            int i = i0 + q;
            if (i < K) {
                u64 w = __shfl(mask, i >> 6);
                bool suppressed = (w >> (i & 63)) & 1ull;
                u64 rowv = r[q];
                int nxt = i + 16;
                r[q] = (owner && nxt < K) ? sup[(size_t)nxt * 16 + lane] : 0ull;
                if (!suppressed) {
                    if (lane == 0) keep[nk] = i;
                    ++nk;
                    mask |= rowv;
                }
            }
        }
    }
    if (lane == 0) *a.nkeep[l] = nk;
}

// ============ L4: emit (verbatim r12) =======================================
struct EArgs {
    const float* ts[5];
    const float* boxes[5];
    const int* keep[5];
    const int* nkeep[5];
    float* ob;
    float* os;
};

__global__ __launch_bounds__(256) void k_emit(EArgs a) {
    int l = blockIdx.x;
    int nk = *a.nkeep[l];
    for (int r = threadIdx.x; r < 1000; r += 256) {
        float b0 = 0, b1 = 0, b2 = 0, b3 = 0, s = -1000000000.0f;
        if (r < nk) {
            int j = a.keep[l][r];
            const float* bp = &a.boxes[l][(size_t)j * 4];
            b0 = bp[0];
            b1 = bp[1];
            b2 = bp[2];
            b3 = bp[3];
            s = a.ts[l][j];
        }
        float* op = &a.ob[(size_t)(l * 1000 + r) * 4];
        op[0] = b0;
        op[1] = b1;
        op[2] = b2;
        op[3] = b3;
        a.os[l * 1000 + r] = s;
    }
}

// ============ L5: final top-1000 via one-block bitonic sort of 8192 =========
__global__ __launch_bounds__(1024) void k_final(const float* __restrict__ ob,
                                                const float* __restrict__ os,
                                                float* __restrict__ out) {
    __shared__ u64 sk[8192];
    int tid = threadIdx.x;
    for (int i = tid; i < 8192; i += 1024)
        sk[i] = (i < 5000) ? (((u64)fkey32(os[i]) << 32) | (u32)(~(u32)i)) : 0ull;
    __syncthreads();
    for (int k2 = 2; k2 <= 8192; k2 <<= 1)
        for (int j = k2 >> 1; j > 0; j >>= 1) {
            for (int i = tid; i < 8192; i += 1024) {
                int p2 = i ^ j;
                if (p2 > i) {
                    u64 va = sk[i], vb = sk[p2];
                    if ((va < vb) == ((i & k2) == 0)) {
                        sk[i] = vb;
                        sk[p2] = va;
                    }
                }
            }
            __syncthreads();
        }
    if (tid < 1000) {
        u64 v = sk[tid];
        u32 gi = ~(u32)(v & 0xffffffffu);
        float s = os[gi];
        const float* b = &ob[(size_t)gi * 4];
        float x1 = b[0], y1 = b[1], x2 = b[2], y2 = b[3];
        out[tid * 4 + 0] = x1;
        out[tid * 4 + 1] = y1;
        out[tid * 4 + 2] = x2;
        out[tid * 4 + 3] = y2;
        out[4000 + tid] = s;
        float area = __fmul_rn(__fadd_rn(__fsub_rn(x2, x1), 1.0f),
                               __fadd_rn(__fsub_rn(y2, y1), 1.0f));
        float scale = __fsqrt_rn(fmaxf(area, 1.0f));
        float t = __fadd_rn(__fdiv_rn(scale, 224.0f), 1e-6f);
        float lv = floorf(__fadd_rn(4.0f, log2f(t)));
        lv = fminf(fmaxf(lv, 2.0f), 5.0f);
        out[5000 + tid] = lv;
    }
}

// ============ host ==========================================================
extern "C" void kernel_launch(void* const* d_in, const int* in_sizes, int n_in,
                              void* d_out, int out_size, void* d_ws, size_t ws_size,
                              hipStream_t stream) {
    const float *fp2 = nullptr, *fp3 = nullptr, *fp4 = nullptr, *fp5 = nullptr, *fp6 = nullptr;
    const float *im_info = nullptr, *conv_w = nullptr, *conv_b = nullptr;
    const float *cls_w = nullptr, *cls_b = nullptr, *bbox_w = nullptr, *bbox_b = nullptr;
    for (int i = 0; i < n_in; ++i) {
        const float* p = (const float*)d_in[i];
        switch (in_sizes[i]) {
            case 16777216: fp2 = p; break;
            case 4194304: fp3 = p; break;
            case 1048576: fp4 = p; break;
            case 262144: fp5 = p; break;
            case 65536: fp6 = p; break;
            case 3: im_info = p; break;
            case 589824: conv_w = p; break;
            case 256: conv_b = p; break;
            case 1536: cls_w = p; break;
            case 6: cls_b = p; break;
            case 3072: bbox_w = p; break;
            case 12: bbox_b = p; break;
            default: break;
        }
    }
    const float* feats[5] = {fp2, fp3, fp4, fp5, fp6};

    size_t off = 0;
    auto take = [&](size_t bytes) -> void* {
        void* p = (char*)d_ws + off;
        off += (bytes + 255) & ~(size_t)255;
        return p;
    };
    float* wT = (float*)take((size_t)2304 * 256 * 4);
    int Hs[5] = {256, 128, 64, 32, 16};
    float* scores[5];
    float* deltas[5];
    float* ts[5];
    float* boxes[5];
    float* areas[5];
    int* keep[5];
    int* nkeep[5];
    u64* sup[5];
    int Narr[5], Karr[5];
    for (int s = 0; s < 5; ++s) {
        int H = Hs[s];
        int N = 3 * H * H;
        Narr[s] = N;
        Karr[s] = N < 1000 ? N : 1000;
        scores[s] = (float*)take((size_t)N * 4);
        deltas[s] = (float*)take((size_t)N * 16);
        ts[s] = (float*)take(1024 * 4);
        boxes[s] = (float*)take(1024 * 16);
        areas[s] = (float*)take(1024 * 4);
        keep[s] = (int*)take(1024 * 4);
        nkeep[s] = (int*)take(256);
        sup[s] = (u64*)take((size_t)1000 * 16 * 8);
    }
    float* ob = (float*)take((size_t)5000 * 16);
    float* os = (float*)take((size_t)5000 * 4);
    u32* h12 = (u32*)take(5 * 4096 * 4);
    u32* h24 = (u32*)take(5 * 4096 * 4);
    u32* h8 = (u32*)take(5 * 256 * 4);
    u32* selst = (u32*)take(5 * 4 * 4);
    u32* T32 = (u32*)take(5 * 4);
    u64* cand = (u64*)take((size_t)5 * CAP * 8);
    u32* ccnt = (u32*)take(5 * 4);

    double anc[5][12];
    for (int s = 0; s < 5; ++s) {
        int lvl = 2 + s;
        double stride = (double)(1 << lvl);
        double xc = 0.5 * (stride - 1.0);
        const double ratios[3] = {0.5, 1.0, 2.0};
        for (int rr = 0; rr < 3; ++rr) {
            double wsv = rint(sqrt(stride * stride / ratios[rr]));
            double hsv = rint(wsv * ratios[rr]);
            double WS = wsv * 8.0, HS = hsv * 8.0;
            anc[s][rr * 4 + 0] = xc - 0.5 * (WS - 1.0);
            anc[s][rr * 4 + 1] = xc - 0.5 * (HS - 1.0);
            anc[s][rr * 4 + 2] = xc + 0.5 * (WS - 1.0);
            anc[s][rr * 4 + 3] = xc + 0.5 * (HS - 1.0);
        }
    }

    k_transpose_w<<<dim3(2304), dim3(256), 0, stream>>>(conv_w, wT);
    for (int s = 0; s < 5; ++s) {
        int H = Hs[s];
        k_conv_heads<<<dim3(H * H / 16), dim3(256), 0, stream>>>(
            feats[s], wT, conv_b, cls_w, cls_b, bbox_w, bbox_b,
            scores[s], deltas[s], H, H);
    }

    SelArgs sa;
    TArgs a2;
    IArgs a3;
    GArgs a4;
    EArgs a5;
    for (int s = 0; s < 5; ++s) {
        sa.sc[s] = scores[s];
        sa.N[s] = Narr[s];
        sa.K[s] = Karr[s];
        sa.needT[s] = (Narr[s] > CAP) ? 1 : 0;
        a2.dl[s] = deltas[s];
        a2.ts[s] = ts[s];
        a2.boxes[s] = boxes[s];
        a2.areas[s] = areas[s];
        a2.K[s] = Karr[s];
        a2.W[s] = Hs[s];
        a2.stride[s] = (float)(1 << (2 + s));
        for (int q = 0; q < 12; ++q) a2.anc[s][q] = (float)anc[s][q];
        a3.boxes[s] = boxes[s];
        a3.areas[s] = areas[s];
        a3.sup[s] = sup[s];
        a3.K[s] = Karr[s];
        a4.sup[s] = sup[s];
        a4.K[s] = Karr[s];
        a4.keep[s] = keep[s];
        a4.nkeep[s] = nkeep[s];
        a5.ts[s] = ts[s];
        a5.boxes[s] = boxes[s];
        a5.keep[s] = keep[s];
        a5.nkeep[s] = nkeep[s];
    }
    sa.h12 = h12;
    sa.h24 = h24;
    sa.h8 = h8;
    sa.selst = selst;
    sa.T32 = T32;
    sa.cand = cand;
    sa.ccnt = ccnt;
    a2.cand = cand;
    a2.ccnt = ccnt;
    a2.im_info = im_info;
    a5.ob = ob;
    a5.os = os;

    int fb = (NTOT + 255) / 256;
    k_zero<<<dim3((5 * 4096 + 255) / 256), dim3(256), 0, stream>>>(sa);
    k_h12<<<dim3(fb), dim3(256), 0, stream>>>(sa);
    k_sel12<<<dim3(5), dim3(1024), 0, stream>>>(sa);
    k_h24<<<dim3(fb), dim3(256), 0, stream>>>(sa);
    k_sel24<<<dim3(5), dim3(1024), 0, stream>>>(sa);
    k_h8<<<dim3(fb), dim3(256), 0, stream>>>(sa);
    k_sel8<<<dim3(5), dim3(256), 0, stream>>>(sa);
    k_compact<<<dim3(fb), dim3(256), 0, stream>>>(sa);
    k_sortdecode<<<dim3(5), dim3(1024), 0, stream>>>(a2);
    k_iou<<<dim3(5000), dim3(256), 0, stream>>>(a3);
    k_nms_scan<<<dim3(5), dim3(64), 0, stream>>>(a4);
    k_emit<<<dim3(5), dim3(256), 0, stream>>>(a5);
    k_final<<<dim3(1), dim3(1024), 0, stream>>>(ob, os, (float*)d_out);
}

// Round 14
// 4633.443 us; speedup vs baseline: 6.8455x; 1.0980x over previous
//
#include <hip/hip_runtime.h>
#include <math.h>
#include <stdint.h>

typedef unsigned long long u64;
typedef unsigned int u32;

#define CAP 4096
#define NTOT 261888  // 196608+49152+12288+3072+768

__device__ __forceinline__ u32 fkey32(float f) {
    u32 u = __float_as_uint(f);
    return (u & 0x80000000u) ? ~u : (u | 0x80000000u);
}

// ---------------- weight transpose ------------------------------------------
__global__ __launch_bounds__(256) void k_transpose_w(const float* __restrict__ w,
                                                     float* __restrict__ wT) {
    int t = blockIdx.x * 256 + threadIdx.x;
    if (t >= 2304 * 256) return;
    int kidx = t >> 8;
    int oc = t & 255;
    wT[t] = w[oc * 2304 + kidx];
}

// ======== L1: fused all-level conv3x3(f64 acc)+relu+heads, 3 blocks/CU ======
// Arithmetic chain per position is VERBATIM r13 (bit-exact verified).
struct CArgs {
    const float* x[5];
    float* scores[5];
    float* deltas[5];
    const float* wT;
    const float* cb;
    const float* clsw;
    const float* clsb;
    const float* bbw;
    const float* bbb;
};

__global__ __launch_bounds__(256, 3) void k_conv_heads(CArgs ca) {
    __shared__ __align__(16) float xs[64][3][20];  // 15360 B
    __shared__ double hs[256][17];                 // 34816 B
    __shared__ double hout[18][16];                // 2304 B  => 52480 B total

    int b = blockIdx.x;
    int l, rel;
    if (b < 4096) { l = 0; rel = b; }
    else if (b < 5120) { l = 1; rel = b - 4096; }
    else if (b < 5376) { l = 2; rel = b - 5120; }
    else if (b < 5440) { l = 3; rel = b - 5376; }
    else { l = 4; rel = b - 5440; }
    const int HWs[5] = {256, 128, 64, 32, 16};
    int H = HWs[l], W = H;
    const float* __restrict__ x = ca.x[l];
    float* __restrict__ scores = ca.scores[l];
    float* __restrict__ deltas = ca.deltas[l];
    const float* __restrict__ wT = ca.wT;

    int tid = threadIdx.x;
    int pos0 = rel * 16;
    int row = pos0 / W;
    int col0 = pos0 % W;

    double acc[16];
#pragma unroll
    for (int p = 0; p < 16; ++p) acc[p] = 0.0;

    for (int cc = 0; cc < 4; ++cc) {
        __syncthreads();
        for (int t = tid; t < 64 * 3 * 20; t += 256) {
            int a = t / 60;
            int r = t % 60;
            int dy = r / 20;
            int dxx = r % 20;
            float v = 0.f;
            int gy = row - 1 + dy;
            int gx = col0 - 1 + dxx;
            if (dxx < 18 && gy >= 0 && gy < H && gx >= 0 && gx < W)
                v = x[((size_t)(cc * 64 + a) * H + gy) * W + gx];
            xs[a][dy][dxx] = v;
        }
        __syncthreads();
        int oc = tid;
        for (int a = 0; a < 64; ++a) {
#pragma unroll
            for (int dy = 0; dy < 3; ++dy) {
                double xr[18];
#pragma unroll
                for (int q = 0; q < 18; ++q) xr[q] = (double)xs[a][dy][q];
                const float* wrow = &wT[((size_t)(cc * 64 + a) * 9 + dy * 3) * 256 + oc];
                double w0 = (double)wrow[0];
                double w1 = (double)wrow[256];
                double w2 = (double)wrow[512];
#pragma unroll
                for (int p = 0; p < 16; ++p) {
                    acc[p] = fma(w0, xr[p], acc[p]);
                    acc[p] = fma(w1, xr[p + 1], acc[p]);
                    acc[p] = fma(w2, xr[p + 2], acc[p]);
                }
            }
        }
    }
    __syncthreads();
    {
        double bias = (double)ca.cb[tid];
#pragma unroll
        for (int p = 0; p < 16; ++p) hs[tid][p] = fmax(acc[p] + bias, 0.0);
    }
    __syncthreads();
    for (int t = tid; t < 288; t += 256) {
        int p = t & 15, ch = t >> 4;
        double s = (ch < 6) ? (double)ca.clsb[ch] : (double)ca.bbb[ch - 6];
        const float* __restrict__ wv =
            (ch < 6) ? (ca.clsw + ch * 256) : (ca.bbw + (ch - 6) * 256);
        for (int ci = 0; ci < 256; ++ci) s += (double)wv[ci] * hs[ci][p];
        hout[ch][p] = s;
    }
    __syncthreads();
    for (int t = tid; t < 48; t += 256) {
        int p = t & 15, a = t >> 4;
        int posi = pos0 + p;
        float c0 = (float)hout[a][p], c1 = (float)hout[3 + a][p];
        float m = fmaxf(c0, c1);
        float e0 = expf(__fsub_rn(c0, m));
        float e1 = expf(__fsub_rn(c1, m));
        scores[(size_t)posi * 3 + a] = __fdiv_rn(e1, __fadd_rn(e0, e1));
    }
    for (int t = tid; t < 192; t += 256) {
        int p = t & 15, j = t >> 4;
        int posi = pos0 + p;
        int a = j >> 2, c = j & 3;
        deltas[((size_t)posi * 3 + a) * 4 + c] = (float)hout[6 + j][p];
    }
}

// ============ top-K selection machinery (verbatim r13) ======================
struct SelArgs {
    const float* sc[5];
    u32* h12;
    u32* h24;
    u32* h8;
    u32* selst;
    u32* T32;
    u64* cand;
    u32* ccnt;
    int N[5], K[5];
    int needT[5];
};

__device__ __forceinline__ void lvl_lookup(int g, int& l, int& base) {
    if (g < 196608) { l = 0; base = 0; }
    else if (g < 245760) { l = 1; base = 196608; }
    else if (g < 258048) { l = 2; base = 245760; }
    else if (g < 261120) { l = 3; base = 258048; }
    else { l = 4; base = 261120; }
}

__global__ __launch_bounds__(256) void k_zero(SelArgs a) {
    int g = blockIdx.x * 256 + threadIdx.x;
    if (g < 5 * 4096) { a.h12[g] = 0; a.h24[g] = 0; }
    if (g < 5 * 256) a.h8[g] = 0;
    if (g < 5) a.ccnt[g] = 0;
}

__global__ __launch_bounds__(256) void k_h12(SelArgs a) {
    int g = blockIdx.x * 256 + threadIdx.x;
    if (g >= NTOT) return;
    int l, base;
    lvl_lookup(g, l, base);
    if (!a.needT[l]) return;
    u32 key = __float_as_uint(a.sc[l][g - base]);
    atomicAdd(&a.h12[l * 4096 + (key >> 20)], 1u);
}

__global__ __launch_bounds__(1024) void k_sel12(SelArgs a) {
    __shared__ u32 h[4096];
    int l = blockIdx.x;
    if (!a.needT[l]) return;
    for (int i = threadIdx.x; i < 4096; i += 1024) h[i] = a.h12[l * 4096 + i];
    __syncthreads();
    if (threadIdx.x == 0) {
        u32 K = (u32)a.K[l], c = 0;
        for (int b = 4095; b >= 0; --b) {
            c += h[b];
            if (c >= K) {
                a.selst[l * 4 + 0] = (u32)b;
                a.selst[l * 4 + 1] = K - (c - h[b]);
                break;
            }
        }
    }
}

__global__ __launch_bounds__(256) void k_h24(SelArgs a) {
    int g = blockIdx.x * 256 + threadIdx.x;
    if (g >= NTOT) return;
    int l, base;
    lvl_lookup(g, l, base);
    if (!a.needT[l]) return;
    u32 key = __float_as_uint(a.sc[l][g - base]);
    if ((key >> 20) == a.selst[l * 4 + 0])
        atomicAdd(&a.h24[l * 4096 + ((key >> 8) & 0xFFFu)], 1u);
}

__global__ __launch_bounds__(1024) void k_sel24(SelArgs a) {
    __shared__ u32 h[4096];
    int l = blockIdx.x;
    if (!a.needT[l]) return;
    for (int i = threadIdx.x; i < 4096; i += 1024) h[i] = a.h24[l * 4096 + i];
    __syncthreads();
    if (threadIdx.x == 0) {
        u32 want = a.selst[l * 4 + 1], c = 0;
        for (int b = 4095; b >= 0; --b) {
            c += h[b];
            if (c >= want) {
                a.selst[l * 4 + 2] = (a.selst[l * 4 + 0] << 12) | (u32)b;
                a.selst[l * 4 + 3] = want - (c - h[b]);
                break;
            }
        }
    }
}

__global__ __launch_bounds__(256) void k_h8(SelArgs a) {
    int g = blockIdx.x * 256 + threadIdx.x;
    if (g >= NTOT) return;
    int l, base;
    lvl_lookup(g, l, base);
    if (!a.needT[l]) return;
    u32 key = __float_as_uint(a.sc[l][g - base]);
    if ((key >> 8) == a.selst[l * 4 + 2])
        atomicAdd(&a.h8[l * 256 + (key & 0xFFu)], 1u);
}

__global__ __launch_bounds__(256) void k_sel8(SelArgs a) {
    __shared__ u32 h[256];
    int l = blockIdx.x;
    if (!a.needT[l]) {
        if (threadIdx.x == 0) a.T32[l] = 0u;
        return;
    }
    if (threadIdx.x < 256) h[threadIdx.x] = a.h8[l * 256 + threadIdx.x];
    __syncthreads();
    if (threadIdx.x == 0) {
        u32 want = a.selst[l * 4 + 3], c = 0;
        for (int b = 255; b >= 0; --b) {
            c += h[b];
            if (c >= want) {
                a.T32[l] = (a.selst[l * 4 + 2] << 8) | (u32)b;
                break;
            }
        }
    }
}

__global__ __launch_bounds__(256) void k_compact(SelArgs a) {
    int g = blockIdx.x * 256 + threadIdx.x;
    if (g >= NTOT) return;
    int l, base;
    lvl_lookup(g, l, base);
    int i = g - base;
    u32 key = __float_as_uint(a.sc[l][i]);
    if (key >= a.T32[l]) {
        u32 p = atomicAdd(&a.ccnt[l], 1u);
        if (p < CAP) a.cand[l * CAP + p] = ((u64)key << 32) | (u32)(~(u32)i);
    }
}

// ============ L2b: sort candidates + decode (verbatim r13) ==================
struct TArgs {
    const u64* cand;
    const u32* ccnt;
    const float* dl[5];
    float* ts[5];
    float* boxes[5];
    float* areas[5];
    int K[5], W[5];
    float stride[5];
    float anc[5][12];
    const float* im_info;
};

__global__ __launch_bounds__(1024) void k_sortdecode(TArgs a) {
    __shared__ u64 sk[CAP];
    int l = blockIdx.x;
    int tid = threadIdx.x;
    u32 cnt = a.ccnt[l];
    if (cnt > CAP) cnt = CAP;
    for (int i = tid; i < CAP; i += 1024)
        sk[i] = (i < (int)cnt) ? a.cand[l * CAP + i] : 0ull;
    __syncthreads();
    for (int k2 = 2; k2 <= CAP; k2 <<= 1)
        for (int j = k2 >> 1; j > 0; j >>= 1) {
            for (int i = tid; i < CAP; i += 1024) {
                int p2 = i ^ j;
                if (p2 > i) {
                    u64 va = sk[i], vb = sk[p2];
                    if ((va < vb) == ((i & k2) == 0)) {
                        sk[i] = vb;
                        sk[p2] = va;
                    }
                }
            }
            __syncthreads();
        }
    int K = a.K[l];
    float imh = a.im_info[0], imw = a.im_info[1];
    float hi_x = __fsub_rn(imw, 1.0f), hi_y = __fsub_rn(imh, 1.0f);
    if (tid < K) {
        u64 v = sk[tid];
        u32 idx = ~(u32)(v & 0xffffffffu);
        float score = __uint_as_float((u32)(v >> 32));
        a.ts[l][tid] = score;
        int aidx = idx % 3;
        int posi = idx / 3;
        int W = a.W[l];
        int rr = posi / W, cc = posi % W;
        float sx = __fmul_rn((float)cc, a.stride[l]);
        float sy = __fmul_rn((float)rr, a.stride[l]);
        const float* an = &a.anc[l][aidx * 4];
        float ax1 = __fadd_rn(an[0], sx), ay1 = __fadd_rn(an[1], sy);
        float ax2 = __fadd_rn(an[2], sx), ay2 = __fadd_rn(an[3], sy);
        float w = __fadd_rn(__fsub_rn(ax2, ax1), 1.0f);
        float h = __fadd_rn(__fsub_rn(ay2, ay1), 1.0f);
        float cx = __fadd_rn(ax1, __fmul_rn(0.5f, w));
        float cy = __fadd_rn(ay1, __fmul_rn(0.5f, h));
        const float* d = &a.dl[l][(size_t)idx * 4];
        float dx = d[0], dy = d[1];
        float dw = fminf(d[2], 4.135166556742356f);
        float dh = fminf(d[3], 4.135166556742356f);
        float pcx = __fadd_rn(__fmul_rn(dx, w), cx);
        float pcy = __fadd_rn(__fmul_rn(dy, h), cy);
        float pw = __fmul_rn(expf(dw), w);
        float ph = __fmul_rn(expf(dh), h);
        float hw2 = __fmul_rn(0.5f, pw), hh2 = __fmul_rn(0.5f, ph);
        float x1 = __fsub_rn(pcx, hw2);
        float y1 = __fsub_rn(pcy, hh2);
        float x2 = __fsub_rn(__fadd_rn(pcx, hw2), 1.0f);
        float y2 = __fsub_rn(__fadd_rn(pcy, hh2), 1.0f);
        x1 = fminf(fmaxf(x1, 0.0f), hi_x);
        y1 = fminf(fmaxf(y1, 0.0f), hi_y);
        x2 = fminf(fmaxf(x2, 0.0f), hi_x);
        y2 = fminf(fmaxf(y2, 0.0f), hi_y);
        float* obx = &a.boxes[l][(size_t)tid * 4];
        obx[0] = x1;
        obx[1] = y1;
        obx[2] = x2;
        obx[3] = y2;
        a.areas[l][tid] = __fmul_rn(__fadd_rn(__fsub_rn(x2, x1), 1.0f),
                                    __fadd_rn(__fsub_rn(y2, y1), 1.0f));
    }
}

// ============ L3a: IoU suppression bit-matrix (verbatim r13) ================
struct IArgs {
    const float* boxes[5];
    const float* areas[5];
    u64* sup[5];
    int K[5];
};

__global__ __launch_bounds__(256) void k_iou(IArgs a) {
    int bx = blockIdx.x;
    int l = bx / 1000;
    int i = bx % 1000;
    int K = a.K[l];
    if (i >= K) return;
    const float* bi = &a.boxes[l][(size_t)i * 4];
    float x1 = bi[0], y1 = bi[1], x2 = bi[2], y2 = bi[3];
    float ai = a.areas[l][i];
    int lane = threadIdx.x & 63;
    int wv = threadIdx.x >> 6;
#pragma unroll
    for (int it = 0; it < 4; ++it) {
        int j = it * 256 + wv * 64 + lane;
        bool sup = false;
        if (j > i && j < K) {
            const float* bj = &a.boxes[l][(size_t)j * 4];
            float xx1 = fmaxf(x1, bj[0]);
            float yy1 = fmaxf(y1, bj[1]);
            float xx2 = fminf(x2, bj[2]);
            float yy2 = fminf(y2, bj[3]);
            float iw = fmaxf(0.0f, __fadd_rn(__fsub_rn(xx2, xx1), 1.0f));
            float ih = fmaxf(0.0f, __fadd_rn(__fsub_rn(yy2, yy1), 1.0f));
            float inter = __fmul_rn(iw, ih);
            float uni = __fsub_rn(__fadd_rn(ai, a.areas[l][j]), inter);
            float iou = __fdiv_rn(inter, uni);
            sup = iou > 0.7f;
        }
        u64 m = __ballot(sup);
        if (lane == 0) a.sup[l][(size_t)i * 16 + it * 4 + wv] = m;
    }
}

// ============ L3b: greedy NMS scan (verbatim r13) ===========================
struct GArgs {
    const u64* sup[5];
    int K[5];
    int* keep[5];
    int* nkeep[5];
};

__global__ __launch_bounds__(64) void k_nms_scan(GArgs a) {
    int l = blockIdx.x;
    int K = a.K[l];
    const u64* __restrict__ sup = a.sup[l];
    int lane = threadIdx.x;
    bool owner = lane < 16;
    u64 mask = 0ull;
    int nk = 0;
    int* keep = a.keep[l];
    u64 r[16];
#pragma unroll
    for (int q = 0; q < 16; ++q)
        r[q] = (owner && q < K) ? sup[(size_t)q * 16 + lane] : 0ull;
    for (int i0 = 0; i0 < K; i0 += 16) {
#pragma unroll
        for (int q = 0; q < 16; ++q) {
            int i = i0 + q;
            if (i < K) {
                u64 w = __shfl(mask, i >> 6);
                bool suppressed = (w >> (i & 63)) & 1ull;
                u64 rowv = r[q];
                int nxt = i + 16;
                r[q] = (owner && nxt < K) ? sup[(size_t)nxt * 16 + lane] : 0ull;
                if (!suppressed) {
                    if (lane == 0) keep[nk] = i;
                    ++nk;
                    mask |= rowv;
                }
            }
        }
    }
    if (lane == 0) *a.nkeep[l] = nk;
}

// ============ L4: emit (verbatim r13) =======================================
struct EArgs {
    const float* ts[5];
    const float* boxes[5];
    const int* keep[5];
    const int* nkeep[5];
    float* ob;
    float* os;
};

__global__ __launch_bounds__(256) void k_emit(EArgs a) {
    int l = blockIdx.x;
    int nk = *a.nkeep[l];
    for (int r = threadIdx.x; r < 1000; r += 256) {
        float b0 = 0, b1 = 0, b2 = 0, b3 = 0, s = -1000000000.0f;
        if (r < nk) {
            int j = a.keep[l][r];
            const float* bp = &a.boxes[l][(size_t)j * 4];
            b0 = bp[0];
            b1 = bp[1];
            b2 = bp[2];
            b3 = bp[3];
            s = a.ts[l][j];
        }
        float* op = &a.ob[(size_t)(l * 1000 + r) * 4];
        op[0] = b0;
        op[1] = b1;
        op[2] = b2;
        op[3] = b3;
        a.os[l * 1000 + r] = s;
    }
}

// ============ L5: final top-1000 (verbatim r13) =============================
__global__ __launch_bounds__(1024) void k_final(const float* __restrict__ ob,
                                                const float* __restrict__ os,
                                                float* __restrict__ out) {
    __shared__ u64 sk[8192];
    int tid = threadIdx.x;
    for (int i = tid; i < 8192; i += 1024)
        sk[i] = (i < 5000) ? (((u64)fkey32(os[i]) << 32) | (u32)(~(u32)i)) : 0ull;
    __syncthreads();
    for (int k2 = 2; k2 <= 8192; k2 <<= 1)
        for (int j = k2 >> 1; j > 0; j >>= 1) {
            for (int i = tid; i < 8192; i += 1024) {
                int p2 = i ^ j;
                if (p2 > i) {
                    u64 va = sk[i], vb = sk[p2];
                    if ((va < vb) == ((i & k2) == 0)) {
                        sk[i] = vb;
                        sk[p2] = va;
                    }
                }
            }
            __syncthreads();
        }
    if (tid < 1000) {
        u64 v = sk[tid];
        u32 gi = ~(u32)(v & 0xffffffffu);
        float s = os[gi];
        const float* b = &ob[(size_t)gi * 4];
        float x1 = b[0], y1 = b[1], x2 = b[2], y2 = b[3];
        out[tid * 4 + 0] = x1;
        out[tid * 4 + 1] = y1;
        out[tid * 4 + 2] = x2;
        out[tid * 4 + 3] = y2;
        out[4000 + tid] = s;
        float area = __fmul_rn(__fadd_rn(__fsub_rn(x2, x1), 1.0f),
                               __fadd_rn(__fsub_rn(y2, y1), 1.0f));
        float scale = __fsqrt_rn(fmaxf(area, 1.0f));
        float t = __fadd_rn(__fdiv_rn(scale, 224.0f), 1e-6f);
        float lv = floorf(__fadd_rn(4.0f, log2f(t)));
        lv = fminf(fmaxf(lv, 2.0f), 5.0f);
        out[5000 + tid] = lv;
    }
}

// ============ host ==========================================================
extern "C" void kernel_launch(void* const* d_in, const int* in_sizes, int n_in,
                              void* d_out, int out_size, void* d_ws, size_t ws_size,
                              hipStream_t stream) {
    const float *fp2 = nullptr, *fp3 = nullptr, *fp4 = nullptr, *fp5 = nullptr, *fp6 = nullptr;
    const float *im_info = nullptr, *conv_w = nullptr, *conv_b = nullptr;
    const float *cls_w = nullptr, *cls_b = nullptr, *bbox_w = nullptr, *bbox_b = nullptr;
    for (int i = 0; i < n_in; ++i) {
        const float* p = (const float*)d_in[i];
        switch (in_sizes[i]) {
            case 16777216: fp2 = p; break;
            case 4194304: fp3 = p; break;
            case 1048576: fp4 = p; break;
            case 262144: fp5 = p; break;
            case 65536: fp6 = p; break;
            case 3: im_info = p; break;
            case 589824: conv_w = p; break;
            case 256: conv_b = p; break;
            case 1536: cls_w = p; break;
            case 6: cls_b = p; break;
            case 3072: bbox_w = p; break;
            case 12: bbox_b = p; break;
            default: break;
        }
    }
    const float* feats[5] = {fp2, fp3, fp4, fp5, fp6};

    size_t off = 0;
    auto take = [&](size_t bytes) -> void* {
        void* p = (char*)d_ws + off;
        off += (bytes + 255) & ~(size_t)255;
        return p;
    };
    float* wT = (float*)take((size_t)2304 * 256 * 4);
    int Hs[5] = {256, 128, 64, 32, 16};
    float* scores[5];
    float* deltas[5];
    float* ts[5];
    float* boxes[5];
    float* areas[5];
    int* keep[5];
    int* nkeep[5];
    u64* sup[5];
    int Narr[5], Karr[5];
    for (int s = 0; s < 5; ++s) {
        int H = Hs[s];
        int N = 3 * H * H;
        Narr[s] = N;
        Karr[s] = N < 1000 ? N : 1000;
        scores[s] = (float*)take((size_t)N * 4);
        deltas[s] = (float*)take((size_t)N * 16);
        ts[s] = (float*)take(1024 * 4);
        boxes[s] = (float*)take(1024 * 16);
        areas[s] = (float*)take(1024 * 4);
        keep[s] = (int*)take(1024 * 4);
        nkeep[s] = (int*)take(256);
        sup[s] = (u64*)take((size_t)1000 * 16 * 8);
    }
    float* ob = (float*)take((size_t)5000 * 16);
    float* os = (float*)take((size_t)5000 * 4);
    u32* h12 = (u32*)take(5 * 4096 * 4);
    u32* h24 = (u32*)take(5 * 4096 * 4);
    u32* h8 = (u32*)take(5 * 256 * 4);
    u32* selst = (u32*)take(5 * 4 * 4);
    u32* T32 = (u32*)take(5 * 4);
    u64* cand = (u64*)take((size_t)5 * CAP * 8);
    u32* ccnt = (u32*)take(5 * 4);

    double anc[5][12];
    for (int s = 0; s < 5; ++s) {
        int lvl = 2 + s;
        double stride = (double)(1 << lvl);
        double xc = 0.5 * (stride - 1.0);
        const double ratios[3] = {0.5, 1.0, 2.0};
        for (int rr = 0; rr < 3; ++rr) {
            double wsv = rint(sqrt(stride * stride / ratios[rr]));
            double hsv = rint(wsv * ratios[rr]);
            double WS = wsv * 8.0, HS = hsv * 8.0;
            anc[s][rr * 4 + 0] = xc - 0.5 * (WS - 1.0);
            anc[s][rr * 4 + 1] = xc - 0.5 * (HS - 1.0);
            anc[s][rr * 4 + 2] = xc + 0.5 * (WS - 1.0);
            anc[s][rr * 4 + 3] = xc + 0.5 * (HS - 1.0);
        }
    }

    k_transpose_w<<<dim3(2304), dim3(256), 0, stream>>>(conv_w, wT);

    CArgs ca;
    for (int s = 0; s < 5; ++s) {
        ca.x[s] = feats[s];
        ca.scores[s] = scores[s];
        ca.deltas[s] = deltas[s];
    }
    ca.wT = wT;
    ca.cb = conv_b;
    ca.clsw = cls_w;
    ca.clsb = cls_b;
    ca.bbw = bbox_w;
    ca.bbb = bbox_b;
    k_conv_heads<<<dim3(5456), dim3(256), 0, stream>>>(ca);

    SelArgs sa;
    TArgs a2;
    IArgs a3;
    GArgs a4;
    EArgs a5;
    for (int s = 0; s < 5; ++s) {
        sa.sc[s] = scores[s];
        sa.N[s] = Narr[s];
        sa.K[s] = Karr[s];
        sa.needT[s] = (Narr[s] > CAP) ? 1 : 0;
        a2.dl[s] = deltas[s];
        a2.ts[s] = ts[s];
        a2.boxes[s] = boxes[s];
        a2.areas[s] = areas[s];
        a2.K[s] = Karr[s];
        a2.W[s] = Hs[s];
        a2.stride[s] = (float)(1 << (2 + s));
        for (int q = 0; q < 12; ++q) a2.anc[s][q] = (float)anc[s][q];
        a3.boxes[s] = boxes[s];
        a3.areas[s] = areas[s];
        a3.sup[s] = sup[s];
        a3.K[s] = Karr[s];
        a4.sup[s] = sup[s];
        a4.K[s] = Karr[s];
        a4.keep[s] = keep[s];
        a4.nkeep[s] = nkeep[s];
        a5.ts[s] = ts[s];
        a5.boxes[s] = boxes[s];
        a5.keep[s] = keep[s];
        a5.nkeep[s] = nkeep[s];
    }
    sa.h12 = h12;
    sa.h24 = h24;
    sa.h8 = h8;
    sa.selst = selst;
    sa.T32 = T32;
    sa.cand = cand;
    sa.ccnt = ccnt;
    a2.cand = cand;
    a2.ccnt = ccnt;
    a2.im_info = im_info;
    a5.ob = ob;
    a5.os = os;

    int fb = (NTOT + 255) / 256;
    k_zero<<<dim3((5 * 4096 + 255) / 256), dim3(256), 0, stream>>>(sa);
    k_h12<<<dim3(fb), dim3(256), 0, stream>>>(sa);
    k_sel12<<<dim3(5), dim3(1024), 0, stream>>>(sa);
    k_h24<<<dim3(fb), dim3(256), 0, stream>>>(sa);
    k_sel24<<<dim3(5), dim3(1024), 0, stream>>>(sa);
    k_h8<<<dim3(fb), dim3(256), 0, stream>>>(sa);
    k_sel8<<<dim3(5), dim3(256), 0, stream>>>(sa);
    k_compact<<<dim3(fb), dim3(256), 0, stream>>>(sa);
    k_sortdecode<<<dim3(5), dim3(1024), 0, stream>>>(a2);
    k_iou<<<dim3(5000), dim3(256), 0, stream>>>(a3);
    k_nms_scan<<<dim3(5), dim3(64), 0, stream>>>(a4);
    k_emit<<<dim3(5), dim3(256), 0, stream>>>(a5);
    k_final<<<dim3(1), dim3(1024), 0, stream>>>(ob, os, (float*)d_out);
}

// Round 15
// 3254.977 us; speedup vs baseline: 9.7446x; 1.4235x over previous
//
#include <hip/hip_runtime.h>
#include <math.h>
#include <stdint.h>

typedef unsigned long long u64;
typedef unsigned int u32;

#define CAP 4096
#define NTOT 261888  // 196608+49152+12288+3072+768

__device__ __forceinline__ u32 fkey32(float f) {
    u32 u = __float_as_uint(f);
    return (u & 0x80000000u) ? ~u : (u | 0x80000000u);
}

// ---------------- weight transpose -> f64: wTd[(ci*9+d)*256+oc] ------------
__global__ __launch_bounds__(256) void k_transpose_w(const float* __restrict__ w,
                                                     double* __restrict__ wTd) {
    int t = blockIdx.x * 256 + threadIdx.x;
    if (t >= 2304 * 256) return;
    int kidx = t >> 8;
    int oc = t & 255;
    wTd[t] = (double)w[oc * 2304 + kidx];
}

// ======== L1: fused all-level conv3x3(f64 acc)+relu+heads, 3 blocks/CU ======
// f64 (w,x) fma chain per output VERBATIM r14 (bit-exact verified); weight
// f32->f64 cvt hoisted into k_transpose_w (exact conversion, same values).
struct CArgs {
    const float* x[5];
    float* scores[5];
    float* deltas[5];
    const double* wTd;
    const float* cb;
    const float* clsw;
    const float* clsb;
    const float* bbw;
    const float* bbb;
};

__global__ __launch_bounds__(256, 3) void k_conv_heads(CArgs ca) {
    __shared__ __align__(16) float xs[64][3][20];  // 15360 B
    __shared__ double hs[256][17];                 // 34816 B
    __shared__ double hout[18][16];                // 2304 B => 52480 B

    int b = blockIdx.x;
    int l, rel;
    if (b < 4096) { l = 0; rel = b; }
    else if (b < 5120) { l = 1; rel = b - 4096; }
    else if (b < 5376) { l = 2; rel = b - 5120; }
    else if (b < 5440) { l = 3; rel = b - 5376; }
    else { l = 4; rel = b - 5440; }
    const int HWs[5] = {256, 128, 64, 32, 16};
    int H = HWs[l], W = H;
    const float* __restrict__ x = ca.x[l];
    float* __restrict__ scores = ca.scores[l];
    float* __restrict__ deltas = ca.deltas[l];
    const double* __restrict__ wTd = ca.wTd;

    int tid = threadIdx.x;
    int pos0 = rel * 16;
    int row = pos0 / W;
    int col0 = pos0 % W;

    double acc[16];
#pragma unroll
    for (int p = 0; p < 16; ++p) acc[p] = 0.0;

    for (int cc = 0; cc < 4; ++cc) {
        __syncthreads();
        for (int t = tid; t < 64 * 3 * 20; t += 256) {
            int a = t / 60;
            int r = t % 60;
            int dy = r / 20;
            int dxx = r % 20;
            float v = 0.f;
            int gy = row - 1 + dy;
            int gx = col0 - 1 + dxx;
            if (dxx < 18 && gy >= 0 && gy < H && gx >= 0 && gx < W)
                v = x[((size_t)(cc * 64 + a) * H + gy) * W + gx];
            xs[a][dy][dxx] = v;
        }
        __syncthreads();
        int oc = tid;
        for (int a = 0; a < 64; ++a) {
#pragma unroll
            for (int dy = 0; dy < 3; ++dy) {
                double xr[18];
#pragma unroll
                for (int q = 0; q < 18; ++q) xr[q] = (double)xs[a][dy][q];
                const double* wrow = &wTd[((size_t)(cc * 64 + a) * 9 + dy * 3) * 256 + oc];
                double w0 = wrow[0];
                double w1 = wrow[256];
                double w2 = wrow[512];
#pragma unroll
                for (int p = 0; p < 16; ++p) {
                    acc[p] = fma(w0, xr[p], acc[p]);
                    acc[p] = fma(w1, xr[p + 1], acc[p]);
                    acc[p] = fma(w2, xr[p + 2], acc[p]);
                }
            }
        }
    }
    __syncthreads();
    {
        double bias = (double)ca.cb[tid];
#pragma unroll
        for (int p = 0; p < 16; ++p) hs[tid][p] = fmax(acc[p] + bias, 0.0);
    }
    __syncthreads();
    for (int t = tid; t < 288; t += 256) {
        int p = t & 15, ch = t >> 4;
        double s = (ch < 6) ? (double)ca.clsb[ch] : (double)ca.bbb[ch - 6];
        const float* __restrict__ wv =
            (ch < 6) ? (ca.clsw + ch * 256) : (ca.bbw + (ch - 6) * 256);
        for (int ci = 0; ci < 256; ++ci) s += (double)wv[ci] * hs[ci][p];
        hout[ch][p] = s;
    }
    __syncthreads();
    for (int t = tid; t < 48; t += 256) {
        int p = t & 15, a = t >> 4;
        int posi = pos0 + p;
        float c0 = (float)hout[a][p], c1 = (float)hout[3 + a][p];
        float m = fmaxf(c0, c1);
        float e0 = expf(__fsub_rn(c0, m));
        float e1 = expf(__fsub_rn(c1, m));
        scores[(size_t)posi * 3 + a] = __fdiv_rn(e1, __fadd_rn(e0, e1));
    }
    for (int t = tid; t < 192; t += 256) {
        int p = t & 15, j = t >> 4;
        int posi = pos0 + p;
        int a = j >> 2, c = j & 3;
        deltas[((size_t)posi * 3 + a) * 4 + c] = (float)hout[6 + j][p];
    }
}

// ============ top-K selection machinery =====================================
struct SelArgs {
    const float* sc[5];
    u32* h12;
    u32* h24;
    u32* h8;
    u32* selst;
    u32* T32;
    u64* cand;
    u32* ccnt;
    int N[5], K[5];
    int needT[5];
};

__device__ __forceinline__ void lvl_lookup(int g, int& l, int& base) {
    if (g < 196608) { l = 0; base = 0; }
    else if (g < 245760) { l = 1; base = 196608; }
    else if (g < 258048) { l = 2; base = 245760; }
    else if (g < 261120) { l = 3; base = 258048; }
    else { l = 4; base = 261120; }
}

// hist blocks: 4096 items each, level-aligned: l0=48 blocks, l1=12, l2=3 (=63)
__device__ __forceinline__ void hblk_lookup(int b, int& l, int& base, int& n0) {
    if (b < 48) { l = 0; base = 0; n0 = b * 4096; }
    else if (b < 60) { l = 1; base = 196608; n0 = (b - 48) * 4096; }
    else { l = 2; base = 245760; n0 = (b - 60) * 4096; }
}

__global__ __launch_bounds__(256) void k_zero(SelArgs a) {
    int g = blockIdx.x * 256 + threadIdx.x;
    if (g < 5 * 4096) { a.h12[g] = 0; a.h24[g] = 0; }
    if (g < 5 * 256) a.h8[g] = 0;
    if (g < 5) a.ccnt[g] = 0;
}

// ---- LDS-privatized 12-bit histogram (levels 0..2 only; l3/l4 need no T) ---
__global__ __launch_bounds__(256) void k_h12(SelArgs a) {
    __shared__ u32 hist[4096];
    int l, base, n0;
    hblk_lookup(blockIdx.x, l, base, n0);
    int tid = threadIdx.x;
    for (int i = tid; i < 4096; i += 256) hist[i] = 0;
    __syncthreads();
    const float* sc = a.sc[l];
    int i0 = n0 + tid;
#pragma unroll
    for (int q = 0; q < 16; ++q) {
        u32 key = __float_as_uint(sc[i0 + q * 256]);
        atomicAdd(&hist[key >> 20], 1u);
    }
    __syncthreads();
    for (int i = tid; i < 4096; i += 256) {
        u32 c = hist[i];
        if (c) atomicAdd(&a.h12[l * 4096 + i], c);
    }
}

__global__ __launch_bounds__(1024) void k_sel12(SelArgs a) {
    __shared__ u32 h[4096];
    int l = blockIdx.x;
    if (!a.needT[l]) return;
    for (int i = threadIdx.x; i < 4096; i += 1024) h[i] = a.h12[l * 4096 + i];
    __syncthreads();
    if (threadIdx.x == 0) {
        u32 K = (u32)a.K[l], c = 0;
        for (int b = 4095; b >= 0; --b) {
            c += h[b];
            if (c >= K) {
                a.selst[l * 4 + 0] = (u32)b;
                a.selst[l * 4 + 1] = K - (c - h[b]);
                break;
            }
        }
    }
}

// ---- LDS-privatized mid-12-bit histogram (filtered to selected top bin) ----
__global__ __launch_bounds__(256) void k_h24(SelArgs a) {
    __shared__ u32 hist[4096];
    int l, base, n0;
    hblk_lookup(blockIdx.x, l, base, n0);
    int tid = threadIdx.x;
    for (int i = tid; i < 4096; i += 256) hist[i] = 0;
    __syncthreads();
    const float* sc = a.sc[l];
    u32 topbin = a.selst[l * 4 + 0];
    int i0 = n0 + tid;
#pragma unroll
    for (int q = 0; q < 16; ++q) {
        u32 key = __float_as_uint(sc[i0 + q * 256]);
        if ((key >> 20) == topbin) atomicAdd(&hist[(key >> 8) & 0xFFFu], 1u);
    }
    __syncthreads();
    for (int i = tid; i < 4096; i += 256) {
        u32 c = hist[i];
        if (c) atomicAdd(&a.h24[l * 4096 + i], c);
    }
}

__global__ __launch_bounds__(1024) void k_sel24(SelArgs a) {
    __shared__ u32 h[4096];
    int l = blockIdx.x;
    if (!a.needT[l]) return;
    for (int i = threadIdx.x; i < 4096; i += 1024) h[i] = a.h24[l * 4096 + i];
    __syncthreads();
    if (threadIdx.x == 0) {
        u32 want = a.selst[l * 4 + 1], c = 0;
        for (int b = 4095; b >= 0; --b) {
            c += h[b];
            if (c >= want) {
                a.selst[l * 4 + 2] = (a.selst[l * 4 + 0] << 12) | (u32)b;
                a.selst[l * 4 + 3] = want - (c - h[b]);
                break;
            }
        }
    }
}

__global__ __launch_bounds__(256) void k_h8(SelArgs a) {
    int g = blockIdx.x * 256 + threadIdx.x;
    if (g >= NTOT) return;
    int l, base;
    lvl_lookup(g, l, base);
    if (!a.needT[l]) return;
    u32 key = __float_as_uint(a.sc[l][g - base]);
    if ((key >> 8) == a.selst[l * 4 + 2])
        atomicAdd(&a.h8[l * 256 + (key & 0xFFu)], 1u);
}

__global__ __launch_bounds__(256) void k_sel8(SelArgs a) {
    __shared__ u32 h[256];
    int l = blockIdx.x;
    if (!a.needT[l]) {
        if (threadIdx.x == 0) a.T32[l] = 0u;
        return;
    }
    if (threadIdx.x < 256) h[threadIdx.x] = a.h8[l * 256 + threadIdx.x];
    __syncthreads();
    if (threadIdx.x == 0) {
        u32 want = a.selst[l * 4 + 3], c = 0;
        for (int b = 255; b >= 0; --b) {
            c += h[b];
            if (c >= want) {
                a.T32[l] = (a.selst[l * 4 + 2] << 8) | (u32)b;
                break;
            }
        }
    }
}

// ---- wave-aggregated compact (order-free: sort canonicalizes) --------------
__global__ __launch_bounds__(256) void k_compact(SelArgs a) {
    int g = blockIdx.x * 256 + threadIdx.x;
    if (g >= NTOT) return;
    int l, base;
    lvl_lookup(g, l, base);  // wave-uniform: level bounds are 256-multiples
    int i = g - base;
    u32 key = __float_as_uint(a.sc[l][i]);
    bool pred = (key >= a.T32[l]);
    u64 mask = __ballot(pred);
    int lane = threadIdx.x & 63;
    u32 cnt = (u32)__popcll(mask);
    u32 basep = 0;
    if (cnt) {
        int leader = __ffsll((long long)mask) - 1;
        if (lane == leader) basep = atomicAdd(&a.ccnt[l], cnt);
        basep = __shfl(basep, leader);
    }
    if (pred) {
        u32 off = (u32)__popcll(mask & ((1ull << lane) - 1ull));
        u32 p = basep + off;
        if (p < CAP) a.cand[l * CAP + p] = ((u64)key << 32) | (u32)(~(u32)i);
    }
}

// ============ L2b: sort candidates + decode (verbatim r14) ==================
struct TArgs {
    const u64* cand;
    const u32* ccnt;
    const float* dl[5];
    float* ts[5];
    float* boxes[5];
    float* areas[5];
    int K[5], W[5];
    float stride[5];
    float anc[5][12];
    const float* im_info;
};

__global__ __launch_bounds__(1024) void k_sortdecode(TArgs a) {
    __shared__ u64 sk[CAP];
    int l = blockIdx.x;
    int tid = threadIdx.x;
    u32 cnt = a.ccnt[l];
    if (cnt > CAP) cnt = CAP;
    for (int i = tid; i < CAP; i += 1024)
        sk[i] = (i < (int)cnt) ? a.cand[l * CAP + i] : 0ull;
    __syncthreads();
    for (int k2 = 2; k2 <= CAP; k2 <<= 1)
        for (int j = k2 >> 1; j > 0; j >>= 1) {
            for (int i = tid; i < CAP; i += 1024) {
                int p2 = i ^ j;
                if (p2 > i) {
                    u64 va = sk[i], vb = sk[p2];
                    if ((va < vb) == ((i & k2) == 0)) {
                        sk[i] = vb;
                        sk[p2] = va;
                    }
                }
            }
            __syncthreads();
        }
    int K = a.K[l];
    float imh = a.im_info[0], imw = a.im_info[1];
    float hi_x = __fsub_rn(imw, 1.0f), hi_y = __fsub_rn(imh, 1.0f);
    if (tid < K) {
        u64 v = sk[tid];
        u32 idx = ~(u32)(v & 0xffffffffu);
        float score = __uint_as_float((u32)(v >> 32));
        a.ts[l][tid] = score;
        int aidx = idx % 3;
        int posi = idx / 3;
        int W = a.W[l];
        int rr = posi / W, cc = posi % W;
        float sx = __fmul_rn((float)cc, a.stride[l]);
        float sy = __fmul_rn((float)rr, a.stride[l]);
        const float* an = &a.anc[l][aidx * 4];
        float ax1 = __fadd_rn(an[0], sx), ay1 = __fadd_rn(an[1], sy);
        float ax2 = __fadd_rn(an[2], sx), ay2 = __fadd_rn(an[3], sy);
        float w = __fadd_rn(__fsub_rn(ax2, ax1), 1.0f);
        float h = __fadd_rn(__fsub_rn(ay2, ay1), 1.0f);
        float cx = __fadd_rn(ax1, __fmul_rn(0.5f, w));
        float cy = __fadd_rn(ay1, __fmul_rn(0.5f, h));
        const float* d = &a.dl[l][(size_t)idx * 4];
        float dx = d[0], dy = d[1];
        float dw = fminf(d[2], 4.135166556742356f);
        float dh = fminf(d[3], 4.135166556742356f);
        float pcx = __fadd_rn(__fmul_rn(dx, w), cx);
        float pcy = __fadd_rn(__fmul_rn(dy, h), cy);
        float pw = __fmul_rn(expf(dw), w);
        float ph = __fmul_rn(expf(dh), h);
        float hw2 = __fmul_rn(0.5f, pw), hh2 = __fmul_rn(0.5f, ph);
        float x1 = __fsub_rn(pcx, hw2);
        float y1 = __fsub_rn(pcy, hh2);
        float x2 = __fsub_rn(__fadd_rn(pcx, hw2), 1.0f);
        float y2 = __fsub_rn(__fadd_rn(pcy, hh2), 1.0f);
        x1 = fminf(fmaxf(x1, 0.0f), hi_x);
        y1 = fminf(fmaxf(y1, 0.0f), hi_y);
        x2 = fminf(fmaxf(x2, 0.0f), hi_x);
        y2 = fminf(fmaxf(y2, 0.0f), hi_y);
        float* obx = &a.boxes[l][(size_t)tid * 4];
        obx[0] = x1;
        obx[1] = y1;
        obx[2] = x2;
        obx[3] = y2;
        a.areas[l][tid] = __fmul_rn(__fadd_rn(__fsub_rn(x2, x1), 1.0f),
                                    __fadd_rn(__fsub_rn(y2, y1), 1.0f));
    }
}

// ============ L3a: IoU suppression bit-matrix (verbatim r14) ================
struct IArgs {
    const float* boxes[5];
    const float* areas[5];
    u64* sup[5];
    int K[5];
};

__global__ __launch_bounds__(256) void k_iou(IArgs a) {
    int bx = blockIdx.x;
    int l = bx / 1000;
    int i = bx % 1000;
    int K = a.K[l];
    if (i >= K) return;
    const float* bi = &a.boxes[l][(size_t)i * 4];
    float x1 = bi[0], y1 = bi[1], x2 = bi[2], y2 = bi[3];
    float ai = a.areas[l][i];
    int lane = threadIdx.x & 63;
    int wv = threadIdx.x >> 6;
#pragma unroll
    for (int it = 0; it < 4; ++it) {
        int j = it * 256 + wv * 64 + lane;
        bool sup = false;
        if (j > i && j < K) {
            const float* bj = &a.boxes[l][(size_t)j * 4];
            float xx1 = fmaxf(x1, bj[0]);
            float yy1 = fmaxf(y1, bj[1]);
            float xx2 = fminf(x2, bj[2]);
            float yy2 = fminf(y2, bj[3]);
            float iw = fmaxf(0.0f, __fadd_rn(__fsub_rn(xx2, xx1), 1.0f));
            float ih = fmaxf(0.0f, __fadd_rn(__fsub_rn(yy2, yy1), 1.0f));
            float inter = __fmul_rn(iw, ih);
            float uni = __fsub_rn(__fadd_rn(ai, a.areas[l][j]), inter);
            float iou = __fdiv_rn(inter, uni);
            sup = iou > 0.7f;
        }
        u64 m = __ballot(sup);
        if (lane == 0) a.sup[l][(size_t)i * 16 + it * 4 + wv] = m;
    }
}

// ============ L3b: greedy NMS scan (verbatim r14) ===========================
struct GArgs {
    const u64* sup[5];
    int K[5];
    int* keep[5];
    int* nkeep[5];
};

__global__ __launch_bounds__(64) void k_nms_scan(GArgs a) {
    int l = blockIdx.x;
    int K = a.K[l];
    const u64* __restrict__ sup = a.sup[l];
    int lane = threadIdx.x;
    bool owner = lane < 16;
    u64 mask = 0ull;
    int nk = 0;
    int* keep = a.keep[l];
    u64 r[16];
#pragma unroll
    for (int q = 0; q < 16; ++q)
        r[q] = (owner && q < K) ? sup[(size_t)q * 16 + lane] : 0ull;
    for (int i0 = 0; i0 < K; i0 += 16) {
#pragma unroll
        for (int q = 0; q < 16; ++q) {
            int i = i0 + q;
            if (i < K) {
                u64 w = __shfl(mask, i >> 6);
                bool suppressed = (w >> (i & 63)) & 1ull;
                u64 rowv = r[q];
                int nxt = i + 16;
                r[q] = (owner && nxt < K) ? sup[(size_t)nxt * 16 + lane] : 0ull;
                if (!suppressed) {
                    if (lane == 0) keep[nk] = i;
                    ++nk;
                    mask |= rowv;
                }
            }
        }
    }
    if (lane == 0) *a.nkeep[l] = nk;
}

// ============ L4: emit (verbatim r14) =======================================
struct EArgs {
    const float* ts[5];
    const float* boxes[5];
    const int* keep[5];
    const int* nkeep[5];
    float* ob;
    float* os;
};

__global__ __launch_bounds__(256) void k_emit(EArgs a) {
    int l = blockIdx.x;
    int nk = *a.nkeep[l];
    for (int r = threadIdx.x; r < 1000; r += 256) {
        float b0 = 0, b1 = 0, b2 = 0, b3 = 0, s = -1000000000.0f;
        if (r < nk) {
            int j = a.keep[l][r];
            const float* bp = &a.boxes[l][(size_t)j * 4];
            b0 = bp[0];
            b1 = bp[1];
            b2 = bp[2];
            b3 = bp[3];
            s = a.ts[l][j];
        }
        float* op = &a.ob[(size_t)(l * 1000 + r) * 4];
        op[0] = b0;
        op[1] = b1;
        op[2] = b2;
        op[3] = b3;
        a.os[l * 1000 + r] = s;
    }
}

// ============ L5: final top-1000 (verbatim r14) =============================
__global__ __launch_bounds__(1024) void k_final(const float* __restrict__ ob,
                                                const float* __restrict__ os,
                                                float* __restrict__ out) {
    __shared__ u64 sk[8192];
    int tid = threadIdx.x;
    for (int i = tid; i < 8192; i += 1024)
        sk[i] = (i < 5000) ? (((u64)fkey32(os[i]) << 32) | (u32)(~(u32)i)) : 0ull;
    __syncthreads();
    for (int k2 = 2; k2 <= 8192; k2 <<= 1)
        for (int j = k2 >> 1; j > 0; j >>= 1) {
            for (int i = tid; i < 8192; i += 1024) {
                int p2 = i ^ j;
                if (p2 > i) {
                    u64 va = sk[i], vb = sk[p2];
                    if ((va < vb) == ((i & k2) == 0)) {
                        sk[i] = vb;
                        sk[p2] = va;
                    }
                }
            }
            __syncthreads();
        }
    if (tid < 1000) {
        u64 v = sk[tid];
        u32 gi = ~(u32)(v & 0xffffffffu);
        float s = os[gi];
        const float* b = &ob[(size_t)gi * 4];
        float x1 = b[0], y1 = b[1], x2 = b[2], y2 = b[3];
        out[tid * 4 + 0] = x1;
        out[tid * 4 + 1] = y1;
        out[tid * 4 + 2] = x2;
        out[tid * 4 + 3] = y2;
        out[4000 + tid] = s;
        float area = __fmul_rn(__fadd_rn(__fsub_rn(x2, x1), 1.0f),
                               __fadd_rn(__fsub_rn(y2, y1), 1.0f));
        float scale = __fsqrt_rn(fmaxf(area, 1.0f));
        float t = __fadd_rn(__fdiv_rn(scale, 224.0f), 1e-6f);
        float lv = floorf(__fadd_rn(4.0f, log2f(t)));
        lv = fminf(fmaxf(lv, 2.0f), 5.0f);
        out[5000 + tid] = lv;
    }
}

// ============ host ==========================================================
extern "C" void kernel_launch(void* const* d_in, const int* in_sizes, int n_in,
                              void* d_out, int out_size, void* d_ws, size_t ws_size,
                              hipStream_t stream) {
    const float *fp2 = nullptr, *fp3 = nullptr, *fp4 = nullptr, *fp5 = nullptr, *fp6 = nullptr;
    const float *im_info = nullptr, *conv_w = nullptr, *conv_b = nullptr;
    const float *cls_w = nullptr, *cls_b = nullptr, *bbox_w = nullptr, *bbox_b = nullptr;
    for (int i = 0; i < n_in; ++i) {
        const float* p = (const float*)d_in[i];
        switch (in_sizes[i]) {
            case 16777216: fp2 = p; break;
            case 4194304: fp3 = p; break;
            case 1048576: fp4 = p; break;
            case 262144: fp5 = p; break;
            case 65536: fp6 = p; break;
            case 3: im_info = p; break;
            case 589824: conv_w = p; break;
            case 256: conv_b = p; break;
            case 1536: cls_w = p; break;
            case 6: cls_b = p; break;
            case 3072: bbox_w = p; break;
            case 12: bbox_b = p; break;
            default: break;
        }
    }
    const float* feats[5] = {fp2, fp3, fp4, fp5, fp6};

    size_t off = 0;
    auto take = [&](size_t bytes) -> void* {
        void* p = (char*)d_ws + off;
        off += (bytes + 255) & ~(size_t)255;
        return p;
    };
    double* wTd = (double*)take((size_t)2304 * 256 * 8);
    int Hs[5] = {256, 128, 64, 32, 16};
    float* scores[5];
    float* deltas[5];
    float* ts[5];
    float* boxes[5];
    float* areas[5];
    int* keep[5];
    int* nkeep[5];
    u64* sup[5];
    int Narr[5], Karr[5];
    for (int s = 0; s < 5; ++s) {
        int H = Hs[s];
        int N = 3 * H * H;
        Narr[s] = N;
        Karr[s] = N < 1000 ? N : 1000;
        scores[s] = (float*)take((size_t)N * 4);
        deltas[s] = (float*)take((size_t)N * 16);
        ts[s] = (float*)take(1024 * 4);
        boxes[s] = (float*)take(1024 * 16);
        areas[s] = (float*)take(1024 * 4);
        keep[s] = (int*)take(1024 * 4);
        nkeep[s] = (int*)take(256);
        sup[s] = (u64*)take((size_t)1000 * 16 * 8);
    }
    float* ob = (float*)take((size_t)5000 * 16);
    float* os = (float*)take((size_t)5000 * 4);
    u32* h12 = (u32*)take(5 * 4096 * 4);
    u32* h24 = (u32*)take(5 * 4096 * 4);
    u32* h8 = (u32*)take(5 * 256 * 4);
    u32* selst = (u32*)take(5 * 4 * 4);
    u32* T32 = (u32*)take(5 * 4);
    u64* cand = (u64*)take((size_t)5 * CAP * 8);
    u32* ccnt = (u32*)take(5 * 4);

    double anc[5][12];
    for (int s = 0; s < 5; ++s) {
        int lvl = 2 + s;
        double stride = (double)(1 << lvl);
        double xc = 0.5 * (stride - 1.0);
        const double ratios[3] = {0.5, 1.0, 2.0};
        for (int rr = 0; rr < 3; ++rr) {
            double wsv = rint(sqrt(stride * stride / ratios[rr]));
            double hsv = rint(wsv * ratios[rr]);
            double WS = wsv * 8.0, HS = hsv * 8.0;
            anc[s][rr * 4 + 0] = xc - 0.5 * (WS - 1.0);
            anc[s][rr * 4 + 1] = xc - 0.5 * (HS - 1.0);
            anc[s][rr * 4 + 2] = xc + 0.5 * (WS - 1.0);
            anc[s][rr * 4 + 3] = xc + 0.5 * (HS - 1.0);
        }
    }

    k_transpose_w<<<dim3(2304), dim3(256), 0, stream>>>(conv_w, wTd);

    CArgs ca;
    for (int s = 0; s < 5; ++s) {
        ca.x[s] = feats[s];
        ca.scores[s] = scores[s];
        ca.deltas[s] = deltas[s];
    }
    ca.wTd = wTd;
    ca.cb = conv_b;
    ca.clsw = cls_w;
    ca.clsb = cls_b;
    ca.bbw = bbox_w;
    ca.bbb = bbox_b;
    k_conv_heads<<<dim3(5456), dim3(256), 0, stream>>>(ca);

    SelArgs sa;
    TArgs a2;
    IArgs a3;
    GArgs a4;
    EArgs a5;
    for (int s = 0; s < 5; ++s) {
        sa.sc[s] = scores[s];
        sa.N[s] = Narr[s];
        sa.K[s] = Karr[s];
        sa.needT[s] = (Narr[s] > CAP) ? 1 : 0;
        a2.dl[s] = deltas[s];
        a2.ts[s] = ts[s];
        a2.boxes[s] = boxes[s];
        a2.areas[s] = areas[s];
        a2.K[s] = Karr[s];
        a2.W[s] = Hs[s];
        a2.stride[s] = (float)(1 << (2 + s));
        for (int q = 0; q < 12; ++q) a2.anc[s][q] = (float)anc[s][q];
        a3.boxes[s] = boxes[s];
        a3.areas[s] = areas[s];
        a3.sup[s] = sup[s];
        a3.K[s] = Karr[s];
        a4.sup[s] = sup[s];
        a4.K[s] = Karr[s];
        a4.keep[s] = keep[s];
        a4.nkeep[s] = nkeep[s];
        a5.ts[s] = ts[s];
        a5.boxes[s] = boxes[s];
        a5.keep[s] = keep[s];
        a5.nkeep[s] = nkeep[s];
    }
    sa.h12 = h12;
    sa.h24 = h24;
    sa.h8 = h8;
    sa.selst = selst;
    sa.T32 = T32;
    sa.cand = cand;
    sa.ccnt = ccnt;
    a2.cand = cand;
    a2.ccnt = ccnt;
    a2.im_info = im_info;
    a5.ob = ob;
    a5.os = os;

    int fb = (NTOT + 255) / 256;
    k_zero<<<dim3((5 * 4096 + 255) / 256), dim3(256), 0, stream>>>(sa);
    k_h12<<<dim3(63), dim3(256), 0, stream>>>(sa);
    k_sel12<<<dim3(5), dim3(1024), 0, stream>>>(sa);
    k_h24<<<dim3(63), dim3(256), 0, stream>>>(sa);
    k_sel24<<<dim3(5), dim3(1024), 0, stream>>>(sa);
    k_h8<<<dim3(fb), dim3(256), 0, stream>>>(sa);
    k_sel8<<<dim3(5), dim3(256), 0, stream>>>(sa);
    k_compact<<<dim3(fb), dim3(256), 0, stream>>>(sa);
    k_sortdecode<<<dim3(5), dim3(1024), 0, stream>>>(a2);
    k_iou<<<dim3(5000), dim3(256), 0, stream>>>(a3);
    k_nms_scan<<<dim3(5), dim3(64), 0, stream>>>(a4);
    k_emit<<<dim3(5), dim3(256), 0, stream>>>(a5);
    k_final<<<dim3(1), dim3(1024), 0, stream>>>(ob, os, (float*)d_out);
}

// Round 16
// 3169.956 us; speedup vs baseline: 10.0059x; 1.0268x over previous
//
#include <hip/hip_runtime.h>
#include <math.h>
#include <stdint.h>

typedef unsigned long long u64;
typedef unsigned int u32;

#define CAP 4096
#define NTOT 261888  // 196608+49152+12288+3072+768

__device__ __forceinline__ u32 fkey32(float f) {
    u32 u = __float_as_uint(f);
    return (u & 0x80000000u) ? ~u : (u | 0x80000000u);
}

// ---------------- weight transpose -> f64: wTd[(ci*9+d)*256+oc] ------------
__global__ __launch_bounds__(256) void k_transpose_w(const float* __restrict__ w,
                                                     double* __restrict__ wTd) {
    int t = blockIdx.x * 256 + threadIdx.x;
    if (t >= 2304 * 256) return;
    int kidx = t >> 8;
    int oc = t & 255;
    wTd[t] = (double)w[oc * 2304 + kidx];
}

// ======== L1: fused all-level conv3x3(f64 acc)+relu+heads, 3 blocks/CU ======
// f64 (w,x) fma chain VERBATIM r15 (bit-exact verified). x f32->f64 cvt now
// done ONCE cooperatively at staging (exact), not per-thread. Head-sum done
// in two p-halves to fit 51.5KB LDS (same ops, same ci order).
struct CArgs {
    const float* x[5];
    float* scores[5];
    float* deltas[5];
    const double* wTd;
    const float* cb;
    const float* clsw;
    const float* clsb;
    const float* bbw;
    const float* bbb;
};

__global__ __launch_bounds__(256, 3) void k_conv_heads(CArgs ca) {
    __shared__ __align__(16) double xs[64][3][20];  // 30720 B (f64, exact cvt)
    __shared__ double hsh[256][9];                  // 18432 B (half-p, padded)
    __shared__ double hout[18][16];                 // 2304 B  => 51456 B

    int b = blockIdx.x;
    int l, rel;
    if (b < 4096) { l = 0; rel = b; }
    else if (b < 5120) { l = 1; rel = b - 4096; }
    else if (b < 5376) { l = 2; rel = b - 5120; }
    else if (b < 5440) { l = 3; rel = b - 5376; }
    else { l = 4; rel = b - 5440; }
    const int HWs[5] = {256, 128, 64, 32, 16};
    int H = HWs[l], W = H;
    const float* __restrict__ x = ca.x[l];
    float* __restrict__ scores = ca.scores[l];
    float* __restrict__ deltas = ca.deltas[l];
    const double* __restrict__ wTd = ca.wTd;

    int tid = threadIdx.x;
    int pos0 = rel * 16;
    int row = pos0 / W;
    int col0 = pos0 % W;

    double acc[16];
#pragma unroll
    for (int p = 0; p < 16; ++p) acc[p] = 0.0;

    for (int cc = 0; cc < 4; ++cc) {
        __syncthreads();
        for (int t = tid; t < 64 * 3 * 20; t += 256) {
            int a = t / 60;
            int r = t % 60;
            int dy = r / 20;
            int dxx = r % 20;
            float v = 0.f;
            int gy = row - 1 + dy;
            int gx = col0 - 1 + dxx;
            if (dxx < 18 && gy >= 0 && gy < H && gx >= 0 && gx < W)
                v = x[((size_t)(cc * 64 + a) * H + gy) * W + gx];
            xs[a][dy][dxx] = (double)v;  // exact conversion, done once
        }
        __syncthreads();
        int oc = tid;
        for (int a = 0; a < 64; ++a) {
#pragma unroll
            for (int dy = 0; dy < 3; ++dy) {
                double xr[18];
#pragma unroll
                for (int q = 0; q < 18; ++q) xr[q] = xs[a][dy][q];
                const double* wrow = &wTd[((size_t)(cc * 64 + a) * 9 + dy * 3) * 256 + oc];
                double w0 = wrow[0];
                double w1 = wrow[256];
                double w2 = wrow[512];
#pragma unroll
                for (int p = 0; p < 16; ++p) {
                    acc[p] = fma(w0, xr[p], acc[p]);
                    acc[p] = fma(w1, xr[p + 1], acc[p]);
                    acc[p] = fma(w2, xr[p + 2], acc[p]);
                }
            }
        }
    }
    // ---- heads in two p-halves (same arithmetic & ci order as r15) ----
    double bias = (double)ca.cb[tid];
    __syncthreads();
#pragma unroll
    for (int p = 0; p < 8; ++p) hsh[tid][p] = fmax(acc[p] + bias, 0.0);
    __syncthreads();
    for (int t = tid; t < 144; t += 256) {
        int p = t & 7, ch = t >> 3;
        double s = (ch < 6) ? (double)ca.clsb[ch] : (double)ca.bbb[ch - 6];
        const float* __restrict__ wv =
            (ch < 6) ? (ca.clsw + ch * 256) : (ca.bbw + (ch - 6) * 256);
        for (int ci = 0; ci < 256; ++ci) s += (double)wv[ci] * hsh[ci][p];
        hout[ch][p] = s;
    }
    __syncthreads();
#pragma unroll
    for (int p = 8; p < 16; ++p) hsh[tid][p - 8] = fmax(acc[p] + bias, 0.0);
    __syncthreads();
    for (int t = tid; t < 144; t += 256) {
        int p = (t & 7) + 8, ch = t >> 3;
        double s = (ch < 6) ? (double)ca.clsb[ch] : (double)ca.bbb[ch - 6];
        const float* __restrict__ wv =
            (ch < 6) ? (ca.clsw + ch * 256) : (ca.bbw + (ch - 6) * 256);
        for (int ci = 0; ci < 256; ++ci) s += (double)wv[ci] * hsh[ci][p - 8];
        hout[ch][p] = s;
    }
    __syncthreads();
    for (int t = tid; t < 48; t += 256) {
        int p = t & 15, a = t >> 4;
        int posi = pos0 + p;
        float c0 = (float)hout[a][p], c1 = (float)hout[3 + a][p];
        float m = fmaxf(c0, c1);
        float e0 = expf(__fsub_rn(c0, m));
        float e1 = expf(__fsub_rn(c1, m));
        scores[(size_t)posi * 3 + a] = __fdiv_rn(e1, __fadd_rn(e0, e1));
    }
    for (int t = tid; t < 192; t += 256) {
        int p = t & 15, j = t >> 4;
        int posi = pos0 + p;
        int a = j >> 2, c = j & 3;
        deltas[((size_t)posi * 3 + a) * 4 + c] = (float)hout[6 + j][p];
    }
}

// ============ top-K selection machinery (verbatim r15) ======================
struct SelArgs {
    const float* sc[5];
    u32* h12;
    u32* h24;
    u32* h8;
    u32* selst;
    u32* T32;
    u64* cand;
    u32* ccnt;
    int N[5], K[5];
    int needT[5];
};

__device__ __forceinline__ void lvl_lookup(int g, int& l, int& base) {
    if (g < 196608) { l = 0; base = 0; }
    else if (g < 245760) { l = 1; base = 196608; }
    else if (g < 258048) { l = 2; base = 245760; }
    else if (g < 261120) { l = 3; base = 258048; }
    else { l = 4; base = 261120; }
}

__device__ __forceinline__ void hblk_lookup(int b, int& l, int& base, int& n0) {
    if (b < 48) { l = 0; base = 0; n0 = b * 4096; }
    else if (b < 60) { l = 1; base = 196608; n0 = (b - 48) * 4096; }
    else { l = 2; base = 245760; n0 = (b - 60) * 4096; }
}

__global__ __launch_bounds__(256) void k_zero(SelArgs a) {
    int g = blockIdx.x * 256 + threadIdx.x;
    if (g < 5 * 4096) { a.h12[g] = 0; a.h24[g] = 0; }
    if (g < 5 * 256) a.h8[g] = 0;
    if (g < 5) a.ccnt[g] = 0;
}

__global__ __launch_bounds__(256) void k_h12(SelArgs a) {
    __shared__ u32 hist[4096];
    int l, base, n0;
    hblk_lookup(blockIdx.x, l, base, n0);
    int tid = threadIdx.x;
    for (int i = tid; i < 4096; i += 256) hist[i] = 0;
    __syncthreads();
    const float* sc = a.sc[l];
    int i0 = n0 + tid;
#pragma unroll
    for (int q = 0; q < 16; ++q) {
        u32 key = __float_as_uint(sc[i0 + q * 256]);
        atomicAdd(&hist[key >> 20], 1u);
    }
    __syncthreads();
    for (int i = tid; i < 4096; i += 256) {
        u32 c = hist[i];
        if (c) atomicAdd(&a.h12[l * 4096 + i], c);
    }
}

__global__ __launch_bounds__(1024) void k_sel12(SelArgs a) {
    __shared__ u32 h[4096];
    int l = blockIdx.x;
    if (!a.needT[l]) return;
    for (int i = threadIdx.x; i < 4096; i += 1024) h[i] = a.h12[l * 4096 + i];
    __syncthreads();
    if (threadIdx.x == 0) {
        u32 K = (u32)a.K[l], c = 0;
        for (int b = 4095; b >= 0; --b) {
            c += h[b];
            if (c >= K) {
                a.selst[l * 4 + 0] = (u32)b;
                a.selst[l * 4 + 1] = K - (c - h[b]);
                break;
            }
        }
    }
}

__global__ __launch_bounds__(256) void k_h24(SelArgs a) {
    __shared__ u32 hist[4096];
    int l, base, n0;
    hblk_lookup(blockIdx.x, l, base, n0);
    int tid = threadIdx.x;
    for (int i = tid; i < 4096; i += 256) hist[i] = 0;
    __syncthreads();
    const float* sc = a.sc[l];
    u32 topbin = a.selst[l * 4 + 0];
    int i0 = n0 + tid;
#pragma unroll
    for (int q = 0; q < 16; ++q) {
        u32 key = __float_as_uint(sc[i0 + q * 256]);
        if ((key >> 20) == topbin) atomicAdd(&hist[(key >> 8) & 0xFFFu], 1u);
    }
    __syncthreads();
    for (int i = tid; i < 4096; i += 256) {
        u32 c = hist[i];
        if (c) atomicAdd(&a.h24[l * 4096 + i], c);
    }
}

__global__ __launch_bounds__(1024) void k_sel24(SelArgs a) {
    __shared__ u32 h[4096];
    int l = blockIdx.x;
    if (!a.needT[l]) return;
    for (int i = threadIdx.x; i < 4096; i += 1024) h[i] = a.h24[l * 4096 + i];
    __syncthreads();
    if (threadIdx.x == 0) {
        u32 want = a.selst[l * 4 + 1], c = 0;
        for (int b = 4095; b >= 0; --b) {
            c += h[b];
            if (c >= want) {
                a.selst[l * 4 + 2] = (a.selst[l * 4 + 0] << 12) | (u32)b;
                a.selst[l * 4 + 3] = want - (c - h[b]);
                break;
            }
        }
    }
}

__global__ __launch_bounds__(256) void k_h8(SelArgs a) {
    int g = blockIdx.x * 256 + threadIdx.x;
    if (g >= NTOT) return;
    int l, base;
    lvl_lookup(g, l, base);
    if (!a.needT[l]) return;
    u32 key = __float_as_uint(a.sc[l][g - base]);
    if ((key >> 8) == a.selst[l * 4 + 2])
        atomicAdd(&a.h8[l * 256 + (key & 0xFFu)], 1u);
}

__global__ __launch_bounds__(256) void k_sel8(SelArgs a) {
    __shared__ u32 h[256];
    int l = blockIdx.x;
    if (!a.needT[l]) {
        if (threadIdx.x == 0) a.T32[l] = 0u;
        return;
    }
    if (threadIdx.x < 256) h[threadIdx.x] = a.h8[l * 256 + threadIdx.x];
    __syncthreads();
    if (threadIdx.x == 0) {
        u32 want = a.selst[l * 4 + 3], c = 0;
        for (int b = 255; b >= 0; --b) {
            c += h[b];
            if (c >= want) {
                a.T32[l] = (a.selst[l * 4 + 2] << 8) | (u32)b;
                break;
            }
        }
    }
}

__global__ __launch_bounds__(256) void k_compact(SelArgs a) {
    int g = blockIdx.x * 256 + threadIdx.x;
    if (g >= NTOT) return;
    int l, base;
    lvl_lookup(g, l, base);
    int i = g - base;
    u32 key = __float_as_uint(a.sc[l][i]);
    bool pred = (key >= a.T32[l]);
    u64 mask = __ballot(pred);
    int lane = threadIdx.x & 63;
    u32 cnt = (u32)__popcll(mask);
    u32 basep = 0;
    if (cnt) {
        int leader = __ffsll((long long)mask) - 1;
        if (lane == leader) basep = atomicAdd(&a.ccnt[l], cnt);
        basep = __shfl(basep, leader);
    }
    if (pred) {
        u32 off = (u32)__popcll(mask & ((1ull << lane) - 1ull));
        u32 p = basep + off;
        if (p < CAP) a.cand[l * CAP + p] = ((u64)key << 32) | (u32)(~(u32)i);
    }
}

// ============ L2b: sort candidates + decode (verbatim r15) ==================
struct TArgs {
    const u64* cand;
    const u32* ccnt;
    const float* dl[5];
    float* ts[5];
    float* boxes[5];
    float* areas[5];
    int K[5], W[5];
    float stride[5];
    float anc[5][12];
    const float* im_info;
};

__global__ __launch_bounds__(1024) void k_sortdecode(TArgs a) {
    __shared__ u64 sk[CAP];
    int l = blockIdx.x;
    int tid = threadIdx.x;
    u32 cnt = a.ccnt[l];
    if (cnt > CAP) cnt = CAP;
    for (int i = tid; i < CAP; i += 1024)
        sk[i] = (i < (int)cnt) ? a.cand[l * CAP + i] : 0ull;
    __syncthreads();
    for (int k2 = 2; k2 <= CAP; k2 <<= 1)
        for (int j = k2 >> 1; j > 0; j >>= 1) {
            for (int i = tid; i < CAP; i += 1024) {
                int p2 = i ^ j;
                if (p2 > i) {
                    u64 va = sk[i], vb = sk[p2];
                    if ((va < vb) == ((i & k2) == 0)) {
                        sk[i] = vb;
                        sk[p2] = va;
                    }
                }
            }
            __syncthreads();
        }
    int K = a.K[l];
    float imh = a.im_info[0], imw = a.im_info[1];
    float hi_x = __fsub_rn(imw, 1.0f), hi_y = __fsub_rn(imh, 1.0f);
    if (tid < K) {
        u64 v = sk[tid];
        u32 idx = ~(u32)(v & 0xffffffffu);
        float score = __uint_as_float((u32)(v >> 32));
        a.ts[l][tid] = score;
        int aidx = idx % 3;
        int posi = idx / 3;
        int W = a.W[l];
        int rr = posi / W, cc = posi % W;
        float sx = __fmul_rn((float)cc, a.stride[l]);
        float sy = __fmul_rn((float)rr, a.stride[l]);
        const float* an = &a.anc[l][aidx * 4];
        float ax1 = __fadd_rn(an[0], sx), ay1 = __fadd_rn(an[1], sy);
        float ax2 = __fadd_rn(an[2], sx), ay2 = __fadd_rn(an[3], sy);
        float w = __fadd_rn(__fsub_rn(ax2, ax1), 1.0f);
        float h = __fadd_rn(__fsub_rn(ay2, ay1), 1.0f);
        float cx = __fadd_rn(ax1, __fmul_rn(0.5f, w));
        float cy = __fadd_rn(ay1, __fmul_rn(0.5f, h));
        const float* d = &a.dl[l][(size_t)idx * 4];
        float dx = d[0], dy = d[1];
        float dw = fminf(d[2], 4.135166556742356f);
        float dh = fminf(d[3], 4.135166556742356f);
        float pcx = __fadd_rn(__fmul_rn(dx, w), cx);
        float pcy = __fadd_rn(__fmul_rn(dy, h), cy);
        float pw = __fmul_rn(expf(dw), w);
        float ph = __fmul_rn(expf(dh), h);
        float hw2 = __fmul_rn(0.5f, pw), hh2 = __fmul_rn(0.5f, ph);
        float x1 = __fsub_rn(pcx, hw2);
        float y1 = __fsub_rn(pcy, hh2);
        float x2 = __fsub_rn(__fadd_rn(pcx, hw2), 1.0f);
        float y2 = __fsub_rn(__fadd_rn(pcy, hh2), 1.0f);
        x1 = fminf(fmaxf(x1, 0.0f), hi_x);
        y1 = fminf(fmaxf(y1, 0.0f), hi_y);
        x2 = fminf(fmaxf(x2, 0.0f), hi_x);
        y2 = fminf(fmaxf(y2, 0.0f), hi_y);
        float* obx = &a.boxes[l][(size_t)tid * 4];
        obx[0] = x1;
        obx[1] = y1;
        obx[2] = x2;
        obx[3] = y2;
        a.areas[l][tid] = __fmul_rn(__fadd_rn(__fsub_rn(x2, x1), 1.0f),
                                    __fadd_rn(__fsub_rn(y2, y1), 1.0f));
    }
}

// ============ L3a: IoU suppression bit-matrix (verbatim r15) ================
struct IArgs {
    const float* boxes[5];
    const float* areas[5];
    u64* sup[5];
    int K[5];
};

__global__ __launch_bounds__(256) void k_iou(IArgs a) {
    int bx = blockIdx.x;
    int l = bx / 1000;
    int i = bx % 1000;
    int K = a.K[l];
    if (i >= K) return;
    const float* bi = &a.boxes[l][(size_t)i * 4];
    float x1 = bi[0], y1 = bi[1], x2 = bi[2], y2 = bi[3];
    float ai = a.areas[l][i];
    int lane = threadIdx.x & 63;
    int wv = threadIdx.x >> 6;
#pragma unroll
    for (int it = 0; it < 4; ++it) {
        int j = it * 256 + wv * 64 + lane;
        bool sup = false;
        if (j > i && j < K) {
            const float* bj = &a.boxes[l][(size_t)j * 4];
            float xx1 = fmaxf(x1, bj[0]);
            float yy1 = fmaxf(y1, bj[1]);
            float xx2 = fminf(x2, bj[2]);
            float yy2 = fminf(y2, bj[3]);
            float iw = fmaxf(0.0f, __fadd_rn(__fsub_rn(xx2, xx1), 1.0f));
            float ih = fmaxf(0.0f, __fadd_rn(__fsub_rn(yy2, yy1), 1.0f));
            float inter = __fmul_rn(iw, ih);
            float uni = __fsub_rn(__fadd_rn(ai, a.areas[l][j]), inter);
            float iou = __fdiv_rn(inter, uni);
            sup = iou > 0.7f;
        }
        u64 m = __ballot(sup);
        if (lane == 0) a.sup[l][(size_t)i * 16 + it * 4 + wv] = m;
    }
}

// ============ L3b: greedy NMS scan (verbatim r15) ===========================
struct GArgs {
    const u64* sup[5];
    int K[5];
    int* keep[5];
    int* nkeep[5];
};

__global__ __launch_bounds__(64) void k_nms_scan(GArgs a) {
    int l = blockIdx.x;
    int K = a.K[l];
    const u64* __restrict__ sup = a.sup[l];
    int lane = threadIdx.x;
    bool owner = lane < 16;
    u64 mask = 0ull;
    int nk = 0;
    int* keep = a.keep[l];
    u64 r[16];
#pragma unroll
    for (int q = 0; q < 16; ++q)
        r[q] = (owner && q < K) ? sup[(size_t)q * 16 + lane] : 0ull;
    for (int i0 = 0; i0 < K; i0 += 16) {
#pragma unroll
        for (int q = 0; q < 16; ++q) {
            int i = i0 + q;
            if (i < K) {
                u64 w = __shfl(mask, i >> 6);
                bool suppressed = (w >> (i & 63)) & 1ull;
                u64 rowv = r[q];
                int nxt = i + 16;
                r[q] = (owner && nxt < K) ? sup[(size_t)nxt * 16 + lane] : 0ull;
                if (!suppressed) {
                    if (lane == 0) keep[nk] = i;
                    ++nk;
                    mask |= rowv;
                }
            }
        }
    }
    if (lane == 0) *a.nkeep[l] = nk;
}

// ============ L4: emit (verbatim r15) =======================================
struct EArgs {
    const float* ts[5];
    const float* boxes[5];
    const int* keep[5];
    const int* nkeep[5];
    float* ob;
    float* os;
};

__global__ __launch_bounds__(256) void k_emit(EArgs a) {
    int l = blockIdx.x;
    int nk = *a.nkeep[l];
    for (int r = threadIdx.x; r < 1000; r += 256) {
        float b0 = 0, b1 = 0, b2 = 0, b3 = 0, s = -1000000000.0f;
        if (r < nk) {
            int j = a.keep[l][r];
            const float* bp = &a.boxes[l][(size_t)j * 4];
            b0 = bp[0];
            b1 = bp[1];
            b2 = bp[2];
            b3 = bp[3];
            s = a.ts[l][j];
        }
        float* op = &a.ob[(size_t)(l * 1000 + r) * 4];
        op[0] = b0;
        op[1] = b1;
        op[2] = b2;
        op[3] = b3;
        a.os[l * 1000 + r] = s;
    }
}

// ============ L5: final top-1000 (verbatim r15) =============================
__global__ __launch_bounds__(1024) void k_final(const float* __restrict__ ob,
                                                const float* __restrict__ os,
                                                float* __restrict__ out) {
    __shared__ u64 sk[8192];
    int tid = threadIdx.x;
    for (int i = tid; i < 8192; i += 1024)
        sk[i] = (i < 5000) ? (((u64)fkey32(os[i]) << 32) | (u32)(~(u32)i)) : 0ull;
    __syncthreads();
    for (int k2 = 2; k2 <= 8192; k2 <<= 1)
        for (int j = k2 >> 1; j > 0; j >>= 1) {
            for (int i = tid; i < 8192; i += 1024) {
                int p2 = i ^ j;
                if (p2 > i) {
                    u64 va = sk[i], vb = sk[p2];
                    if ((va < vb) == ((i & k2) == 0)) {
                        sk[i] = vb;
                        sk[p2] = va;
                    }
                }
            }
            __syncthreads();
        }
    if (tid < 1000) {
        u64 v = sk[tid];
        u32 gi = ~(u32)(v & 0xffffffffu);
        float s = os[gi];
        const float* b = &ob[(size_t)gi * 4];
        float x1 = b[0], y1 = b[1], x2 = b[2], y2 = b[3];
        out[tid * 4 + 0] = x1;
        out[tid * 4 + 1] = y1;
        out[tid * 4 + 2] = x2;
        out[tid * 4 + 3] = y2;
        out[4000 + tid] = s;
        float area = __fmul_rn(__fadd_rn(__fsub_rn(x2, x1), 1.0f),
                               __fadd_rn(__fsub_rn(y2, y1), 1.0f));
        float scale = __fsqrt_rn(fmaxf(area, 1.0f));
        float t = __fadd_rn(__fdiv_rn(scale, 224.0f), 1e-6f);
        float lv = floorf(__fadd_rn(4.0f, log2f(t)));
        lv = fminf(fmaxf(lv, 2.0f), 5.0f);
        out[5000 + tid] = lv;
    }
}

// ============ host ==========================================================
extern "C" void kernel_launch(void* const* d_in, const int* in_sizes, int n_in,
                              void* d_out, int out_size, void* d_ws, size_t ws_size,
                              hipStream_t stream) {
    const float *fp2 = nullptr, *fp3 = nullptr, *fp4 = nullptr, *fp5 = nullptr, *fp6 = nullptr;
    const float *im_info = nullptr, *conv_w = nullptr, *conv_b = nullptr;
    const float *cls_w = nullptr, *cls_b = nullptr, *bbox_w = nullptr, *bbox_b = nullptr;
    for (int i = 0; i < n_in; ++i) {
        const float* p = (const float*)d_in[i];
        switch (in_sizes[i]) {
            case 16777216: fp2 = p; break;
            case 4194304: fp3 = p; break;
            case 1048576: fp4 = p; break;
            case 262144: fp5 = p; break;
            case 65536: fp6 = p; break;
            case 3: im_info = p; break;
            case 589824: conv_w = p; break;
            case 256: conv_b = p; break;
            case 1536: cls_w = p; break;
            case 6: cls_b = p; break;
            case 3072: bbox_w = p; break;
            case 12: bbox_b = p; break;
            default: break;
        }
    }
    const float* feats[5] = {fp2, fp3, fp4, fp5, fp6};

    size_t off = 0;
    auto take = [&](size_t bytes) -> void* {
        void* p = (char*)d_ws + off;
        off += (bytes + 255) & ~(size_t)255;
        return p;
    };
    double* wTd = (double*)take((size_t)2304 * 256 * 8);
    int Hs[5] = {256, 128, 64, 32, 16};
    float* scores[5];
    float* deltas[5];
    float* ts[5];
    float* boxes[5];
    float* areas[5];
    int* keep[5];
    int* nkeep[5];
    u64* sup[5];
    int Narr[5], Karr[5];
    for (int s = 0; s < 5; ++s) {
        int H = Hs[s];
        int N = 3 * H * H;
        Narr[s] = N;
        Karr[s] = N < 1000 ? N : 1000;
        scores[s] = (float*)take((size_t)N * 4);
        deltas[s] = (float*)take((size_t)N * 16);
        ts[s] = (float*)take(1024 * 4);
        boxes[s] = (float*)take(1024 * 16);
        areas[s] = (float*)take(1024 * 4);
        keep[s] = (int*)take(1024 * 4);
        nkeep[s] = (int*)take(256);
        sup[s] = (u64*)take((size_t)1000 * 16 * 8);
    }
    float* ob = (float*)take((size_t)5000 * 16);
    float* os = (float*)take((size_t)5000 * 4);
    u32* h12 = (u32*)take(5 * 4096 * 4);
    u32* h24 = (u32*)take(5 * 4096 * 4);
    u32* h8 = (u32*)take(5 * 256 * 4);
    u32* selst = (u32*)take(5 * 4 * 4);
    u32* T32 = (u32*)take(5 * 4);
    u64* cand = (u64*)take((size_t)5 * CAP * 8);
    u32* ccnt = (u32*)take(5 * 4);

    double anc[5][12];
    for (int s = 0; s < 5; ++s) {
        int lvl = 2 + s;
        double stride = (double)(1 << lvl);
        double xc = 0.5 * (stride - 1.0);
        const double ratios[3] = {0.5, 1.0, 2.0};
        for (int rr = 0; rr < 3; ++rr) {
            double wsv = rint(sqrt(stride * stride / ratios[rr]));
            double hsv = rint(wsv * ratios[rr]);
            double WS = wsv * 8.0, HS = hsv * 8.0;
            anc[s][rr * 4 + 0] = xc - 0.5 * (WS - 1.0);
            anc[s][rr * 4 + 1] = xc - 0.5 * (HS - 1.0);
            anc[s][rr * 4 + 2] = xc + 0.5 * (WS - 1.0);
            anc[s][rr * 4 + 3] = xc + 0.5 * (HS - 1.0);
        }
    }

    SelArgs sa;
    TArgs a2;
    IArgs a3;
    GArgs a4;
    EArgs a5;
    for (int s = 0; s < 5; ++s) {
        sa.sc[s] = scores[s];
        sa.N[s] = Narr[s];
        sa.K[s] = Karr[s];
        sa.needT[s] = (Narr[s] > CAP) ? 1 : 0;
        a2.dl[s] = deltas[s];
        a2.ts[s] = ts[s];
        a2.boxes[s] = boxes[s];
        a2.areas[s] = areas[s];
        a2.K[s] = Karr[s];
        a2.W[s] = Hs[s];
        a2.stride[s] = (float)(1 << (2 + s));
        for (int q = 0; q < 12; ++q) a2.anc[s][q] = (float)anc[s][q];
        a3.boxes[s] = boxes[s];
        a3.areas[s] = areas[s];
        a3.sup[s] = sup[s];
        a3.K[s] = Karr[s];
        a4.sup[s] = sup[s];
        a4.K[s] = Karr[s];
        a4.keep[s] = keep[s];
        a4.nkeep[s] = nkeep[s];
        a5.ts[s] = ts[s];
        a5.boxes[s] = boxes[s];
        a5.keep[s] = keep[s];
        a5.nkeep[s] = nkeep[s];
    }
    sa.h12 = h12;
    sa.h24 = h24;
    sa.h8 = h8;
    sa.selst = selst;
    sa.T32 = T32;
    sa.cand = cand;
    sa.ccnt = ccnt;
    a2.cand = cand;
    a2.ccnt = ccnt;
    a2.im_info = im_info;
    a5.ob = ob;
    a5.os = os;

    k_transpose_w<<<dim3(2304), dim3(256), 0, stream>>>(conv_w, wTd);
    k_zero<<<dim3((5 * 4096 + 255) / 256), dim3(256), 0, stream>>>(sa);

    CArgs ca;
    for (int s = 0; s < 5; ++s) {
        ca.x[s] = feats[s];
        ca.scores[s] = scores[s];
        ca.deltas[s] = deltas[s];
    }
    ca.wTd = wTd;
    ca.cb = conv_b;
    ca.clsw = cls_w;
    ca.clsb = cls_b;
    ca.bbw = bbox_w;
    ca.bbb = bbox_b;
    k_conv_heads<<<dim3(5456), dim3(256), 0, stream>>>(ca);

    int fb = (NTOT + 255) / 256;
    k_h12<<<dim3(63), dim3(256), 0, stream>>>(sa);
    k_sel12<<<dim3(5), dim3(1024), 0, stream>>>(sa);
    k_h24<<<dim3(63), dim3(256), 0, stream>>>(sa);
    k_sel24<<<dim3(5), dim3(1024), 0, stream>>>(sa);
    k_h8<<<dim3(fb), dim3(256), 0, stream>>>(sa);
    k_sel8<<<dim3(5), dim3(256), 0, stream>>>(sa);
    k_compact<<<dim3(fb), dim3(256), 0, stream>>>(sa);
    k_sortdecode<<<dim3(5), dim3(1024), 0, stream>>>(a2);
    k_iou<<<dim3(5000), dim3(256), 0, stream>>>(a3);
    k_nms_scan<<<dim3(5), dim3(64), 0, stream>>>(a4);
    k_emit<<<dim3(5), dim3(256), 0, stream>>>(a5);
    k_final<<<dim3(1), dim3(1024), 0, stream>>>(ob, os, (float*)d_out);
}